// Round 2
// baseline (2992.802 us; speedup 1.0000x reference)
//
#include <hip/hip_runtime.h>
#include <hip/hip_bf16.h>

#define NNODES 32768
#define NEDGES 262144
#define FIN    128
#define HID1   512
#define HID2   1024
#define NGRAPH 1024
#define NCLS   20

// ---- bf16 bit helpers (RNE) ----
__device__ inline float bf2f(unsigned short u) {
    union { unsigned int i; float f; } v; v.i = ((unsigned int)u) << 16; return v.f;
}
__device__ inline unsigned short f2bf(float f) {
    union { unsigned int i; float f; } v; v.f = f;
    unsigned int r = v.i + 0x7FFF + ((v.i >> 16) & 1);
    return (unsigned short)(r >> 16);
}

// ---------------- degree / normalization ----------------
__global__ __launch_bounds__(256) void deg_init(float* deg) {
    int i = blockIdx.x * 256 + threadIdx.x;
    if (i < NNODES) deg[i] = 1.0f;          // self-loop
}
__global__ __launch_bounds__(256) void deg_count(const int* __restrict__ dst, float* deg) {
    int i = blockIdx.x * 256 + threadIdx.x;
    if (i < NEDGES) atomicAdd(&deg[dst[i]], 1.0f);
}
__global__ __launch_bounds__(256) void dis_fin(float* deg) {
    int i = blockIdx.x * 256 + threadIdx.x;
    if (i < NNODES) deg[i] = rsqrtf(deg[i]);
}

// ---------------- aggregation: out(fp32) = A_norm @ X ----------------
// BF: X is bf16 (h1); else fp32 (input x)
template<int F, int BF>
__global__ __launch_bounds__(256) void self_init(const void* __restrict__ Xv,
                                                 const float* __restrict__ dis,
                                                 float* __restrict__ out) {
    int t = blockIdx.x * 256 + threadIdx.x;
    const int total = NNODES * (F / 4);
    if (t >= total) return;
    int i = t / (F / 4);
    float s = dis[i]; s = s * s;            // self-loop norm = dis^2
    float4 v;
    if (BF) {
        ushort4 u = ((const ushort4*)Xv)[t];
        v.x = bf2f(u.x); v.y = bf2f(u.y); v.z = bf2f(u.z); v.w = bf2f(u.w);
    } else {
        v = ((const float4*)Xv)[t];
    }
    v.x *= s; v.y *= s; v.z *= s; v.w *= s;
    ((float4*)out)[t] = v;
}

template<int F, int BF>
__global__ __launch_bounds__(256) void edge_scatter(const void* __restrict__ Xv,
                                                    const int* __restrict__ src,
                                                    const int* __restrict__ dst,
                                                    const float* __restrict__ dis,
                                                    float* __restrict__ out) {
    const int CPT = F / 4;
    long long t = (long long)blockIdx.x * 256 + threadIdx.x;
    if (t >= (long long)NEDGES * CPT) return;
    int e  = (int)(t / CPT);
    int c4 = ((int)(t % CPT)) * 4;
    int s = src[e], d = dst[e];
    float w = dis[s] * dis[d];
    float4 v;
    if (BF) {
        ushort4 u = *(const ushort4*)((const unsigned short*)Xv + (size_t)s * F + c4);
        v.x = bf2f(u.x); v.y = bf2f(u.y); v.z = bf2f(u.z); v.w = bf2f(u.w);
    } else {
        v = *(const float4*)((const float*)Xv + (size_t)s * F + c4);
    }
    float* o = out + (size_t)d * F + c4;
    atomicAdd(o + 0, w * v.x);
    atomicAdd(o + 1, w * v.y);
    atomicAdd(o + 2, w * v.z);
    atomicAdd(o + 3, w * v.w);
}

// ---------------- tiled fp32 GEMM: C = A[MxK] @ B[KxN] + bias ----------------
// EPI=1: relu.  CBF16: store C as bf16.
template<int EPI, int CBF16>
__global__ __launch_bounds__(256) void gemm_f32(const float* __restrict__ A,
                                                const float* __restrict__ B,
                                                const float* __restrict__ bias,
                                                void* __restrict__ Cv,
                                                int M, int N, int K) {
    constexpr int BM = 64, BN = 64, BK = 16;
    __shared__ float As[BK][BM];
    __shared__ float Bs[BK][BN];
    int tid = threadIdx.x;
    int tx = tid & 15, ty = tid >> 4;
    int m0 = blockIdx.y * BM, n0 = blockIdx.x * BN;
    int ar = tid >> 2;            // 0..63 (row within A tile)
    int ak = (tid & 3) * 4;       // k offset
    int bk = tid >> 4;            // 0..15
    int bn = (tid & 15) * 4;
    float acc[4][4] = {};
    for (int k0 = 0; k0 < K; k0 += BK) {
        float4 av = *(const float4*)(A + (size_t)(m0 + ar) * K + k0 + ak);
        float4 bv = *(const float4*)(B + (size_t)(k0 + bk) * N + n0 + bn);
        As[ak + 0][ar] = av.x; As[ak + 1][ar] = av.y;
        As[ak + 2][ar] = av.z; As[ak + 3][ar] = av.w;
        *(float4*)&Bs[bk][bn] = bv;
        __syncthreads();
#pragma unroll
        for (int kk = 0; kk < BK; ++kk) {
            float a[4], b[4];
#pragma unroll
            for (int i = 0; i < 4; ++i) a[i] = As[kk][ty * 4 + i];
#pragma unroll
            for (int j = 0; j < 4; ++j) b[j] = Bs[kk][tx * 4 + j];
#pragma unroll
            for (int i = 0; i < 4; ++i)
#pragma unroll
                for (int j = 0; j < 4; ++j) acc[i][j] += a[i] * b[j];
        }
        __syncthreads();
    }
#pragma unroll
    for (int i = 0; i < 4; ++i) {
        int row = m0 + ty * 4 + i;
        float4 v;
        v.x = acc[i][0] + bias[n0 + tx * 4 + 0];
        v.y = acc[i][1] + bias[n0 + tx * 4 + 1];
        v.z = acc[i][2] + bias[n0 + tx * 4 + 2];
        v.w = acc[i][3] + bias[n0 + tx * 4 + 3];
        if (EPI == 1) {
            v.x = fmaxf(v.x, 0.f); v.y = fmaxf(v.y, 0.f);
            v.z = fmaxf(v.z, 0.f); v.w = fmaxf(v.w, 0.f);
        }
        if (CBF16) {
            ushort4 sv;
            sv.x = f2bf(v.x); sv.y = f2bf(v.y); sv.z = f2bf(v.z); sv.w = f2bf(v.w);
            *(ushort4*)((unsigned short*)Cv + (size_t)row * N + n0 + tx * 4) = sv;
        } else {
            *(float4*)((float*)Cv + (size_t)row * N + n0 + tx * 4) = v;
        }
    }
}

// ---------------- per-column (BatchNorm) stats over bf16 ----------------
__global__ __launch_bounds__(256) void col_stats_b(const unsigned short* __restrict__ X,
                                                   int rows, int cols,
                                                   float* __restrict__ sum, float* __restrict__ sumsq) {
    int col = blockIdx.x * 64 + (threadIdx.x & 63);
    int yt = threadIdx.x >> 6;                 // 0..3
    int rowsPer = rows / (gridDim.y * 4);
    int r0 = (blockIdx.y * 4 + yt) * rowsPer;
    float s = 0.f, ss = 0.f;
    for (int r = r0; r < r0 + rowsPer; ++r) {
        float v = bf2f(X[(size_t)r * cols + col]);
        s += v; ss += v * v;
    }
    atomicAdd(&sum[col], s);
    atomicAdd(&sumsq[col], ss);
}

__global__ void bn_finalize(const float* __restrict__ sum, const float* __restrict__ sq,
                            const float* __restrict__ w, const float* __restrict__ b,
                            float* __restrict__ scale, float* __restrict__ shift,
                            int cols, float invN) {
    int c = blockIdx.x * blockDim.x + threadIdx.x;
    if (c >= cols) return;
    float mu = sum[c] * invN;
    float var = sq[c] * invN - mu * mu;
    float sc = rsqrtf(var + 1e-5f) * w[c];
    scale[c] = sc;
    shift[c] = b[c] - mu * sc;
}

// ---------------- BN apply + ReLU on bf16 (optionally accumulate global LN stats) ----------------
template<bool LNACC>
__global__ __launch_bounds__(256) void bn_apply_b(unsigned short* __restrict__ X,
                                                  const float* __restrict__ scale,
                                                  const float* __restrict__ shift,
                                                  int total4, int c4mask, double* lnacc) {
    float lsum = 0.f, lsq = 0.f;
    for (int t = blockIdx.x * 256 + threadIdx.x; t < total4; t += gridDim.x * 256) {
        int c4 = (t & c4mask) * 4;
        ushort4 u = ((ushort4*)X)[t];
        float4 sc = *(const float4*)(scale + c4);
        float4 sh = *(const float4*)(shift + c4);
        float4 v;
        v.x = fmaxf(bf2f(u.x) * sc.x + sh.x, 0.f);
        v.y = fmaxf(bf2f(u.y) * sc.y + sh.y, 0.f);
        v.z = fmaxf(bf2f(u.z) * sc.z + sh.z, 0.f);
        v.w = fmaxf(bf2f(u.w) * sc.w + sh.w, 0.f);
        u.x = f2bf(v.x); u.y = f2bf(v.y); u.z = f2bf(v.z); u.w = f2bf(v.w);
        ((ushort4*)X)[t] = u;
        if (LNACC) {
            // accumulate on the stored (bf16-rounded) values to match downstream reads
            float a = bf2f(u.x), b = bf2f(u.y), c = bf2f(u.z), d = bf2f(u.w);
            lsum += a + b + c + d;
            lsq  += a * a + b * b + c * c + d * d;
        }
    }
    if (LNACC) {
        for (int o = 32; o > 0; o >>= 1) {
            lsum += __shfl_down(lsum, o);
            lsq  += __shfl_down(lsq, o);
        }
        __shared__ float w1[4], w2[4];
        int wid = threadIdx.x >> 6, lane = threadIdx.x & 63;
        if (lane == 0) { w1[wid] = lsum; w2[wid] = lsq; }
        __syncthreads();
        if (threadIdx.x == 0) {
            atomicAdd(lnacc,     (double)(w1[0] + w1[1] + w1[2] + w1[3]));
            atomicAdd(lnacc + 1, (double)(w2[0] + w2[1] + w2[2] + w2[3]));
        }
    }
}

// ---------------- global stats only (for LN2 over z, fp32) ----------------
__global__ __launch_bounds__(256) void global_stats(const float* __restrict__ X, int total4, double* acc) {
    float s = 0.f, ss = 0.f;
    for (int t = blockIdx.x * 256 + threadIdx.x; t < total4; t += gridDim.x * 256) {
        float4 v = ((const float4*)X)[t];
        s  += v.x + v.y + v.z + v.w;
        ss += v.x * v.x + v.y * v.y + v.z * v.z + v.w * v.w;
    }
    for (int o = 32; o > 0; o >>= 1) {
        s += __shfl_down(s, o);
        ss += __shfl_down(ss, o);
    }
    __shared__ float w1[4], w2[4];
    int wid = threadIdx.x >> 6, lane = threadIdx.x & 63;
    if (lane == 0) { w1[wid] = s; w2[wid] = ss; }
    __syncthreads();
    if (threadIdx.x == 0) {
        atomicAdd(acc,     (double)(w1[0] + w1[1] + w1[2] + w1[3]));
        atomicAdd(acc + 1, (double)(w2[0] + w2[1] + w2[2] + w2[3]));
    }
}

// ---------------- LN finalize: per-channel affine a[c], c[c] ----------------
__global__ void ln_finalize(const double* __restrict__ acc, const float* __restrict__ w,
                            const float* __restrict__ b, float* __restrict__ a,
                            float* __restrict__ c, int cols, double invCount) {
    __shared__ float smu, sinv;
    if (threadIdx.x == 0) {
        double mu  = acc[0] * invCount;
        double var = acc[1] * invCount - mu * mu;
        if (var < 0.0) var = 0.0;
        float stdv = sqrtf((float)var);
        smu = (float)mu;
        sinv = 1.0f / (stdv + 1e-5f);
    }
    __syncthreads();
    int ci = threadIdx.x;
    if (ci < cols) {
        float A = sinv * w[ci];
        a[ci] = A;
        c[ci] = b[ci] - smu * A;
    }
}

// ---------------- fused LN + per-graph max pool (32 contiguous nodes/graph), bf16 in ----------------
__global__ __launch_bounds__(256) void pool_ln_b(const unsigned short* __restrict__ H,
                                                 const float* __restrict__ a,
                                                 const float* __restrict__ c,
                                                 float* __restrict__ P) {
    int g = blockIdx.x;
    int c0 = threadIdx.x * 4;
    float4 av = *(const float4*)(a + c0);
    float4 cv = *(const float4*)(c + c0);
    float4 m = make_float4(-1e30f, -1e30f, -1e30f, -1e30f);
    const unsigned short* row = H + (size_t)g * 32 * HID2 + c0;
    for (int n = 0; n < 32; ++n, row += HID2) {
        ushort4 u = *(const ushort4*)row;
        m.x = fmaxf(m.x, bf2f(u.x) * av.x + cv.x);
        m.y = fmaxf(m.y, bf2f(u.y) * av.y + cv.y);
        m.z = fmaxf(m.z, bf2f(u.z) * av.z + cv.z);
        m.w = fmaxf(m.w, bf2f(u.w) * av.w + cv.w);
    }
    *(float4*)(P + (size_t)g * HID2 + c0) = m;
}

// ---------------- fused LN2 + final GEMM [1024,512]@[512,20] + log_softmax ----------------
__global__ __launch_bounds__(64) void gemm4_lsm(const float* __restrict__ Z,
                                                const float* __restrict__ a,
                                                const float* __restrict__ c,
                                                const float* __restrict__ W,
                                                const float* __restrict__ bias,
                                                float* __restrict__ out) {
    __shared__ float zs[HID1];
    __shared__ float logits[NCLS];
    __shared__ float smax, slse;
    int m = blockIdx.x;
    for (int k = threadIdx.x; k < HID1; k += 64)
        zs[k] = Z[(size_t)m * HID1 + k] * a[k] + c[k];
    __syncthreads();
    if (threadIdx.x < NCLS) {
        float acc = bias[threadIdx.x];
        for (int k = 0; k < HID1; ++k)
            acc += zs[k] * W[k * NCLS + threadIdx.x];
        logits[threadIdx.x] = acc;
    }
    __syncthreads();
    if (threadIdx.x == 0) {
        float mx = -1e30f;
        for (int j = 0; j < NCLS; ++j) mx = fmaxf(mx, logits[j]);
        float s = 0.f;
        for (int j = 0; j < NCLS; ++j) s += expf(logits[j] - mx);
        smax = mx; slse = logf(s);
    }
    __syncthreads();
    if (threadIdx.x < NCLS)
        out[(size_t)m * NCLS + threadIdx.x] = logits[threadIdx.x] - smax - slse;
}

// ======================== launch ========================
extern "C" void kernel_launch(void* const* d_in, const int* in_sizes, int n_in,
                              void* d_out, int out_size, void* d_ws, size_t ws_size,
                              hipStream_t stream) {
    const float* x       = (const float*)d_in[0];
    const int*   ei      = (const int*)d_in[1];
    const int*   src     = ei;
    const int*   dst     = ei + NEDGES;
    const float* conv1_w = (const float*)d_in[3];
    const float* conv1_b = (const float*)d_in[4];
    const float* bn1_w   = (const float*)d_in[5];
    const float* bn1_b   = (const float*)d_in[6];
    const float* conv2_w = (const float*)d_in[7];
    const float* conv2_b = (const float*)d_in[8];
    const float* bn2_w   = (const float*)d_in[9];
    const float* bn2_b   = (const float*)d_in[10];
    const float* ln1_w   = (const float*)d_in[11];
    const float* ln1_b   = (const float*)d_in[12];
    const float* lin1_w  = (const float*)d_in[13];
    const float* lin1_b  = (const float*)d_in[14];
    const float* ln2_w   = (const float*)d_in[15];
    const float* ln2_b   = (const float*)d_in[16];
    const float* lin2_w  = (const float*)d_in[17];
    const float* lin2_b  = (const float*)d_in[18];
    float* out = (float*)d_out;

    // ---- compact workspace layout: 1 MB header + 128 MB buffers = 129 MB total ----
    char* ws = (char*)d_ws;
    const size_t MB = 1ull << 20;
    const size_t BASE = 1 * MB;
    float*          dis  = (float*)(ws + 0);              // 128 KB
    float*          sF   = (float*)(ws + 256 * 1024);     // 40 KB stats
    float*          agg2 = (float*)(ws + BASE);           // [N,512] fp32: BASE+0..64MB
    unsigned short* h2   = (unsigned short*)(ws + BASE + 64 * MB);  // [N,1024] bf16: +64..128MB
    unsigned short* h1   = (unsigned short*)(ws + BASE + 64 * MB);  // [N,512] bf16: +64..96MB (inside h2, dead before gemm2)
    float*          agg1 = (float*)(ws + BASE + 96 * MB); // [N,128] fp32: +96..112MB (inside h2, dead before gemm2)
    float*          pool = (float*)(ws + BASE);           // [G,1024] fp32 overlays agg2 (dead)
    float*          z    = (float*)(ws + BASE + 4 * MB);  // [G,512] fp32

    float* bn1_sum = sF + 0,      *bn1_sq    = sF + 512;
    float* bn1_scale = sF + 1024, *bn1_shift = sF + 1536;
    float* bn2_sum = sF + 2048,   *bn2_sq    = sF + 3072;
    float* bn2_scale = sF + 4096, *bn2_shift = sF + 5120;
    float* ln1_a = sF + 6144, *ln1_c = sF + 7168;
    float* ln2_a = sF + 8192, *ln2_c = sF + 8704;
    double* lnacc = (double*)(sF + 9216);   // [0,1]=ln1  [2,3]=ln2

    hipMemsetAsync(sF, 0, 40960, stream);

    // normalization coefficients
    deg_init<<<(NNODES + 255) / 256, 256, 0, stream>>>(dis);
    deg_count<<<(NEDGES + 255) / 256, 256, 0, stream>>>(dst, dis);
    dis_fin<<<(NNODES + 255) / 256, 256, 0, stream>>>(dis);

    // ---- conv1: agg1 = A @ x ; h1 = agg1 @ W1 + b1 (bf16) ----
    self_init<FIN, 0><<<(NNODES * (FIN / 4) + 255) / 256, 256, 0, stream>>>(x, dis, agg1);
    edge_scatter<FIN, 0><<<(int)(((long long)NEDGES * (FIN / 4) + 255) / 256), 256, 0, stream>>>(x, src, dst, dis, agg1);
    gemm_f32<0, 1><<<dim3(HID1 / 64, NNODES / 64), 256, 0, stream>>>(agg1, conv1_w, conv1_b, h1, NNODES, HID1, FIN);

    // ---- bn1 + relu ----
    col_stats_b<<<dim3(HID1 / 64, 64), 256, 0, stream>>>(h1, NNODES, HID1, bn1_sum, bn1_sq);
    bn_finalize<<<(HID1 + 255) / 256, 256, 0, stream>>>(bn1_sum, bn1_sq, bn1_w, bn1_b, bn1_scale, bn1_shift, HID1, 1.0f / NNODES);
    bn_apply_b<false><<<2048, 256, 0, stream>>>(h1, bn1_scale, bn1_shift, NNODES * HID1 / 4, HID1 / 4 - 1, nullptr);

    // ---- conv2: agg2 = A @ h1 ; h2 = agg2 @ W2 + b2 (bf16) ----
    self_init<HID1, 1><<<(NNODES * (HID1 / 4) + 255) / 256, 256, 0, stream>>>(h1, dis, agg2);
    edge_scatter<HID1, 1><<<(int)(((long long)NEDGES * (HID1 / 4) + 255) / 256), 256, 0, stream>>>(h1, src, dst, dis, agg2);
    gemm_f32<0, 1><<<dim3(HID2 / 64, NNODES / 64), 256, 0, stream>>>(agg2, conv2_w, conv2_b, h2, NNODES, HID2, HID1);

    // ---- bn2 + relu (+ accumulate LN1 global stats) ----
    col_stats_b<<<dim3(HID2 / 64, 64), 256, 0, stream>>>(h2, NNODES, HID2, bn2_sum, bn2_sq);
    bn_finalize<<<(HID2 + 255) / 256, 256, 0, stream>>>(bn2_sum, bn2_sq, bn2_w, bn2_b, bn2_scale, bn2_shift, HID2, 1.0f / NNODES);
    bn_apply_b<true><<<2048, 256, 0, stream>>>(h2, bn2_scale, bn2_shift, NNODES * HID2 / 4, HID2 / 4 - 1, lnacc);

    // ---- LN1 affine + fused pool ----
    ln_finalize<<<1, HID2, 0, stream>>>(lnacc, ln1_w, ln1_b, ln1_a, ln1_c, HID2, 1.0 / ((double)NNODES * HID2));
    pool_ln_b<<<NGRAPH, 256, 0, stream>>>(h2, ln1_a, ln1_c, pool);

    // ---- lin1 + relu (fp32) ----
    gemm_f32<1, 0><<<dim3(HID1 / 64, NGRAPH / 64), 256, 0, stream>>>(pool, lin1_w, lin1_b, z, NGRAPH, HID1, HID2);

    // ---- LN2 + lin2 + log_softmax ----
    global_stats<<<512, 256, 0, stream>>>(z, NGRAPH * HID1 / 4, lnacc + 2);
    ln_finalize<<<1, HID1, 0, stream>>>(lnacc + 2, ln2_w, ln2_b, ln2_a, ln2_c, HID1, 1.0 / ((double)NGRAPH * HID1));
    gemm4_lsm<<<NGRAPH, 64, 0, stream>>>(z, ln2_a, ln2_c, lin2_w, lin2_b, out);
}

// Round 3
// 921.767 us; speedup vs baseline: 3.2468x; 3.2468x over previous
//
#include <hip/hip_runtime.h>
#include <hip/hip_bf16.h>

#define NNODES 32768
#define NEDGES 262144
#define FIN    128
#define HID1   512
#define HID2   1024
#define NGRAPH 1024
#define NCLS   20

// ---- bf16 bit helpers (RNE) ----
__device__ inline float bf2f(unsigned short u) {
    union { unsigned int i; float f; } v; v.i = ((unsigned int)u) << 16; return v.f;
}
__device__ inline unsigned short f2bf(float f) {
    union { unsigned int i; float f; } v; v.f = f;
    unsigned int r = v.i + 0x7FFF + ((v.i >> 16) & 1);
    return (unsigned short)(r >> 16);
}

// ================= CSR build (by dst) =================
__global__ __launch_bounds__(256) void csr_count(const int* __restrict__ dst, int* __restrict__ cnt) {
    int e = blockIdx.x * 256 + threadIdx.x;
    if (e < NEDGES) atomicAdd(&cnt[dst[e]], 1);
}

// single block, 1024 threads, 32 nodes/thread: exclusive scan + dis = rsqrt(cnt+1)
__global__ __launch_bounds__(1024) void csr_scan(const int* __restrict__ cnt,
                                                 int* __restrict__ offs,
                                                 int* __restrict__ cursor,
                                                 float* __restrict__ dis) {
    __shared__ int part[1024];
    int t = threadIdx.x;
    int base = t * 32;
    int s = 0;
#pragma unroll
    for (int i = 0; i < 32; ++i) s += cnt[base + i];
    part[t] = s;
    __syncthreads();
    for (int off = 1; off < 1024; off <<= 1) {
        int v = (t >= off) ? part[t - off] : 0;
        __syncthreads();
        part[t] += v;
        __syncthreads();
    }
    int run = (t == 0) ? 0 : part[t - 1];
#pragma unroll
    for (int i = 0; i < 32; ++i) {
        int c = cnt[base + i];
        offs[base + i] = run;
        cursor[base + i] = run;
        dis[base + i] = rsqrtf((float)(c + 1));
        run += c;
    }
    if (t == 1023) offs[NNODES] = run;
}

__global__ __launch_bounds__(256) void csr_fill(const int* __restrict__ src,
                                                const int* __restrict__ dst,
                                                const float* __restrict__ dis,
                                                int* __restrict__ cursor,
                                                int* __restrict__ csr_src,
                                                float* __restrict__ csr_w) {
    int e = blockIdx.x * 256 + threadIdx.x;
    if (e >= NEDGES) return;
    int s = src[e], d = dst[e];
    int pos = atomicAdd(&cursor[d], 1);
    csr_src[pos] = s;
    csr_w[pos] = dis[s] * dis[d];
}

// ================= gather aggregation: out[i] = dis[i]^2 * X[i] + sum_e w_e * X[src_e] =================
// one wave per node; lane covers CPL = F/64 channels. BFIN: X is bf16. Output fp32.
template<int F, int BFIN>
__global__ __launch_bounds__(256) void gcn_gather(const void* __restrict__ Xv,
                                                  const int* __restrict__ offs,
                                                  const int* __restrict__ csr_src,
                                                  const float* __restrict__ csr_w,
                                                  const float* __restrict__ dis,
                                                  float* __restrict__ out) {
    constexpr int CPL = F / 64;          // 2 (F=128) or 8 (F=512)
    int wave = threadIdx.x >> 6, lane = threadIdx.x & 63;
    int node = blockIdx.x * 4 + wave;
    int c0 = lane * CPL;
    float acc[CPL];
    float sw = dis[node]; sw *= sw;

    if (BFIN) {
        const unsigned short* r = (const unsigned short*)Xv + (size_t)node * F + c0;
#pragma unroll
        for (int q = 0; q < (CPL + 3) / 4; ++q) {
            ushort4 u = *(const ushort4*)(r + q * 4);
            acc[q * 4 + 0] = sw * bf2f(u.x);
            acc[q * 4 + 1] = sw * bf2f(u.y);
            acc[q * 4 + 2] = sw * bf2f(u.z);
            acc[q * 4 + 3] = sw * bf2f(u.w);
        }
    } else if (CPL == 2) {
        float2 u = *(const float2*)((const float*)Xv + (size_t)node * F + c0);
        acc[0] = sw * u.x; acc[1] = sw * u.y;
    } else {
#pragma unroll
        for (int q = 0; q < (CPL + 3) / 4; ++q) {
            float4 u = *(const float4*)((const float*)Xv + (size_t)node * F + c0 + q * 4);
            acc[q * 4 + 0] = sw * u.x; acc[q * 4 + 1] = sw * u.y;
            acc[q * 4 + 2] = sw * u.z; acc[q * 4 + 3] = sw * u.w;
        }
    }

    int e0 = offs[node], e1 = offs[node + 1];
    for (int e = e0; e < e1; ++e) {
        int s = csr_src[e];
        float w = csr_w[e];
        if (BFIN) {
            const unsigned short* r = (const unsigned short*)Xv + (size_t)s * F + c0;
#pragma unroll
            for (int q = 0; q < (CPL + 3) / 4; ++q) {
                ushort4 u = *(const ushort4*)(r + q * 4);
                acc[q * 4 + 0] += w * bf2f(u.x);
                acc[q * 4 + 1] += w * bf2f(u.y);
                acc[q * 4 + 2] += w * bf2f(u.z);
                acc[q * 4 + 3] += w * bf2f(u.w);
            }
        } else if (CPL == 2) {
            float2 u = *(const float2*)((const float*)Xv + (size_t)s * F + c0);
            acc[0] += w * u.x; acc[1] += w * u.y;
        } else {
#pragma unroll
            for (int q = 0; q < (CPL + 3) / 4; ++q) {
                float4 u = *(const float4*)((const float*)Xv + (size_t)s * F + c0 + q * 4);
                acc[q * 4 + 0] += w * u.x; acc[q * 4 + 1] += w * u.y;
                acc[q * 4 + 2] += w * u.z; acc[q * 4 + 3] += w * u.w;
            }
        }
    }

    float* o = out + (size_t)node * F + c0;
    if (CPL == 2) {
        *(float2*)o = make_float2(acc[0], acc[1]);
    } else {
#pragma unroll
        for (int q = 0; q < (CPL + 3) / 4; ++q)
            *(float4*)(o + q * 4) = make_float4(acc[q * 4 + 0], acc[q * 4 + 1], acc[q * 4 + 2], acc[q * 4 + 3]);
    }
}

// ---------------- tiled fp32 GEMM: C = A[MxK] @ B[KxN] + bias ----------------
// EPI=1: relu.  CBF16: store C as bf16.
template<int EPI, int CBF16>
__global__ __launch_bounds__(256) void gemm_f32(const float* __restrict__ A,
                                                const float* __restrict__ B,
                                                const float* __restrict__ bias,
                                                void* __restrict__ Cv,
                                                int M, int N, int K) {
    constexpr int BM = 64, BN = 64, BK = 16;
    __shared__ float As[BK][BM];
    __shared__ float Bs[BK][BN];
    int tid = threadIdx.x;
    int tx = tid & 15, ty = tid >> 4;
    int m0 = blockIdx.y * BM, n0 = blockIdx.x * BN;
    int ar = tid >> 2;            // 0..63 (row within A tile)
    int ak = (tid & 3) * 4;       // k offset
    int bk = tid >> 4;            // 0..15
    int bn = (tid & 15) * 4;
    float acc[4][4] = {};
    for (int k0 = 0; k0 < K; k0 += BK) {
        float4 av = *(const float4*)(A + (size_t)(m0 + ar) * K + k0 + ak);
        float4 bv = *(const float4*)(B + (size_t)(k0 + bk) * N + n0 + bn);
        As[ak + 0][ar] = av.x; As[ak + 1][ar] = av.y;
        As[ak + 2][ar] = av.z; As[ak + 3][ar] = av.w;
        *(float4*)&Bs[bk][bn] = bv;
        __syncthreads();
#pragma unroll
        for (int kk = 0; kk < BK; ++kk) {
            float a[4], b[4];
#pragma unroll
            for (int i = 0; i < 4; ++i) a[i] = As[kk][ty * 4 + i];
#pragma unroll
            for (int j = 0; j < 4; ++j) b[j] = Bs[kk][tx * 4 + j];
#pragma unroll
            for (int i = 0; i < 4; ++i)
#pragma unroll
                for (int j = 0; j < 4; ++j) acc[i][j] += a[i] * b[j];
        }
        __syncthreads();
    }
#pragma unroll
    for (int i = 0; i < 4; ++i) {
        int row = m0 + ty * 4 + i;
        float4 v;
        v.x = acc[i][0] + bias[n0 + tx * 4 + 0];
        v.y = acc[i][1] + bias[n0 + tx * 4 + 1];
        v.z = acc[i][2] + bias[n0 + tx * 4 + 2];
        v.w = acc[i][3] + bias[n0 + tx * 4 + 3];
        if (EPI == 1) {
            v.x = fmaxf(v.x, 0.f); v.y = fmaxf(v.y, 0.f);
            v.z = fmaxf(v.z, 0.f); v.w = fmaxf(v.w, 0.f);
        }
        if (CBF16) {
            ushort4 sv;
            sv.x = f2bf(v.x); sv.y = f2bf(v.y); sv.z = f2bf(v.z); sv.w = f2bf(v.w);
            *(ushort4*)((unsigned short*)Cv + (size_t)row * N + n0 + tx * 4) = sv;
        } else {
            *(float4*)((float*)Cv + (size_t)row * N + n0 + tx * 4) = v;
        }
    }
}

// ---------------- per-column (BatchNorm) stats over bf16 ----------------
__global__ __launch_bounds__(256) void col_stats_b(const unsigned short* __restrict__ X,
                                                   int rows, int cols,
                                                   float* __restrict__ sum, float* __restrict__ sumsq) {
    int col = blockIdx.x * 64 + (threadIdx.x & 63);
    int yt = threadIdx.x >> 6;                 // 0..3
    int rowsPer = rows / (gridDim.y * 4);
    int r0 = (blockIdx.y * 4 + yt) * rowsPer;
    float s = 0.f, ss = 0.f;
    for (int r = r0; r < r0 + rowsPer; ++r) {
        float v = bf2f(X[(size_t)r * cols + col]);
        s += v; ss += v * v;
    }
    atomicAdd(&sum[col], s);
    atomicAdd(&sumsq[col], ss);
}

__global__ void bn_finalize(const float* __restrict__ sum, const float* __restrict__ sq,
                            const float* __restrict__ w, const float* __restrict__ b,
                            float* __restrict__ scale, float* __restrict__ shift,
                            int cols, float invN) {
    int c = blockIdx.x * blockDim.x + threadIdx.x;
    if (c >= cols) return;
    float mu = sum[c] * invN;
    float var = sq[c] * invN - mu * mu;
    float sc = rsqrtf(var + 1e-5f) * w[c];
    scale[c] = sc;
    shift[c] = b[c] - mu * sc;
}

// ---------------- BN apply + ReLU on bf16 (optionally accumulate global LN stats) ----------------
template<bool LNACC>
__global__ __launch_bounds__(256) void bn_apply_b(unsigned short* __restrict__ X,
                                                  const float* __restrict__ scale,
                                                  const float* __restrict__ shift,
                                                  int total4, int c4mask, double* lnacc) {
    float lsum = 0.f, lsq = 0.f;
    for (int t = blockIdx.x * 256 + threadIdx.x; t < total4; t += gridDim.x * 256) {
        int c4 = (t & c4mask) * 4;
        ushort4 u = ((ushort4*)X)[t];
        float4 sc = *(const float4*)(scale + c4);
        float4 sh = *(const float4*)(shift + c4);
        float4 v;
        v.x = fmaxf(bf2f(u.x) * sc.x + sh.x, 0.f);
        v.y = fmaxf(bf2f(u.y) * sc.y + sh.y, 0.f);
        v.z = fmaxf(bf2f(u.z) * sc.z + sh.z, 0.f);
        v.w = fmaxf(bf2f(u.w) * sc.w + sh.w, 0.f);
        u.x = f2bf(v.x); u.y = f2bf(v.y); u.z = f2bf(v.z); u.w = f2bf(v.w);
        ((ushort4*)X)[t] = u;
        if (LNACC) {
            float a = bf2f(u.x), b = bf2f(u.y), c = bf2f(u.z), d = bf2f(u.w);
            lsum += a + b + c + d;
            lsq  += a * a + b * b + c * c + d * d;
        }
    }
    if (LNACC) {
        for (int o = 32; o > 0; o >>= 1) {
            lsum += __shfl_down(lsum, o);
            lsq  += __shfl_down(lsq, o);
        }
        __shared__ float w1[4], w2[4];
        int wid = threadIdx.x >> 6, lane = threadIdx.x & 63;
        if (lane == 0) { w1[wid] = lsum; w2[wid] = lsq; }
        __syncthreads();
        if (threadIdx.x == 0) {
            atomicAdd(lnacc,     (double)(w1[0] + w1[1] + w1[2] + w1[3]));
            atomicAdd(lnacc + 1, (double)(w2[0] + w2[1] + w2[2] + w2[3]));
        }
    }
}

// ---------------- global stats only (for LN2 over z, fp32) ----------------
__global__ __launch_bounds__(256) void global_stats(const float* __restrict__ X, int total4, double* acc) {
    float s = 0.f, ss = 0.f;
    for (int t = blockIdx.x * 256 + threadIdx.x; t < total4; t += gridDim.x * 256) {
        float4 v = ((const float4*)X)[t];
        s  += v.x + v.y + v.z + v.w;
        ss += v.x * v.x + v.y * v.y + v.z * v.z + v.w * v.w;
    }
    for (int o = 32; o > 0; o >>= 1) {
        s += __shfl_down(s, o);
        ss += __shfl_down(ss, o);
    }
    __shared__ float w1[4], w2[4];
    int wid = threadIdx.x >> 6, lane = threadIdx.x & 63;
    if (lane == 0) { w1[wid] = s; w2[wid] = ss; }
    __syncthreads();
    if (threadIdx.x == 0) {
        atomicAdd(acc,     (double)(w1[0] + w1[1] + w1[2] + w1[3]));
        atomicAdd(acc + 1, (double)(w2[0] + w2[1] + w2[2] + w2[3]));
    }
}

// ---------------- LN finalize: per-channel affine a[c], c[c] ----------------
__global__ void ln_finalize(const double* __restrict__ acc, const float* __restrict__ w,
                            const float* __restrict__ b, float* __restrict__ a,
                            float* __restrict__ c, int cols, double invCount) {
    __shared__ float smu, sinv;
    if (threadIdx.x == 0) {
        double mu  = acc[0] * invCount;
        double var = acc[1] * invCount - mu * mu;
        if (var < 0.0) var = 0.0;
        float stdv = sqrtf((float)var);
        smu = (float)mu;
        sinv = 1.0f / (stdv + 1e-5f);
    }
    __syncthreads();
    int ci = threadIdx.x;
    if (ci < cols) {
        float A = sinv * w[ci];
        a[ci] = A;
        c[ci] = b[ci] - smu * A;
    }
}

// ---------------- fused LN + per-graph max pool (32 contiguous nodes/graph), bf16 in ----------------
__global__ __launch_bounds__(256) void pool_ln_b(const unsigned short* __restrict__ H,
                                                 const float* __restrict__ a,
                                                 const float* __restrict__ c,
                                                 float* __restrict__ P) {
    int g = blockIdx.x;
    int c0 = threadIdx.x * 4;
    float4 av = *(const float4*)(a + c0);
    float4 cv = *(const float4*)(c + c0);
    float4 m = make_float4(-1e30f, -1e30f, -1e30f, -1e30f);
    const unsigned short* row = H + (size_t)g * 32 * HID2 + c0;
    for (int n = 0; n < 32; ++n, row += HID2) {
        ushort4 u = *(const ushort4*)row;
        m.x = fmaxf(m.x, bf2f(u.x) * av.x + cv.x);
        m.y = fmaxf(m.y, bf2f(u.y) * av.y + cv.y);
        m.z = fmaxf(m.z, bf2f(u.z) * av.z + cv.z);
        m.w = fmaxf(m.w, bf2f(u.w) * av.w + cv.w);
    }
    *(float4*)(P + (size_t)g * HID2 + c0) = m;
}

// ---------------- fused LN2 + final GEMM [1024,512]@[512,20] + log_softmax ----------------
__global__ __launch_bounds__(64) void gemm4_lsm(const float* __restrict__ Z,
                                                const float* __restrict__ a,
                                                const float* __restrict__ c,
                                                const float* __restrict__ W,
                                                const float* __restrict__ bias,
                                                float* __restrict__ out) {
    __shared__ float zs[HID1];
    __shared__ float logits[NCLS];
    __shared__ float smax, slse;
    int m = blockIdx.x;
    for (int k = threadIdx.x; k < HID1; k += 64)
        zs[k] = Z[(size_t)m * HID1 + k] * a[k] + c[k];
    __syncthreads();
    if (threadIdx.x < NCLS) {
        float acc = bias[threadIdx.x];
        for (int k = 0; k < HID1; ++k)
            acc += zs[k] * W[k * NCLS + threadIdx.x];
        logits[threadIdx.x] = acc;
    }
    __syncthreads();
    if (threadIdx.x == 0) {
        float mx = -1e30f;
        for (int j = 0; j < NCLS; ++j) mx = fmaxf(mx, logits[j]);
        float s = 0.f;
        for (int j = 0; j < NCLS; ++j) s += expf(logits[j] - mx);
        smax = mx; slse = logf(s);
    }
    __syncthreads();
    if (threadIdx.x < NCLS)
        out[(size_t)m * NCLS + threadIdx.x] = logits[threadIdx.x] - smax - slse;
}

// ======================== launch ========================
extern "C" void kernel_launch(void* const* d_in, const int* in_sizes, int n_in,
                              void* d_out, int out_size, void* d_ws, size_t ws_size,
                              hipStream_t stream) {
    const float* x       = (const float*)d_in[0];
    const int*   ei      = (const int*)d_in[1];
    const int*   src     = ei;
    const int*   dst     = ei + NEDGES;
    const float* conv1_w = (const float*)d_in[3];
    const float* conv1_b = (const float*)d_in[4];
    const float* bn1_w   = (const float*)d_in[5];
    const float* bn1_b   = (const float*)d_in[6];
    const float* conv2_w = (const float*)d_in[7];
    const float* conv2_b = (const float*)d_in[8];
    const float* bn2_w   = (const float*)d_in[9];
    const float* bn2_b   = (const float*)d_in[10];
    const float* ln1_w   = (const float*)d_in[11];
    const float* ln1_b   = (const float*)d_in[12];
    const float* lin1_w  = (const float*)d_in[13];
    const float* lin1_b  = (const float*)d_in[14];
    const float* ln2_w   = (const float*)d_in[15];
    const float* ln2_b   = (const float*)d_in[16];
    const float* lin2_w  = (const float*)d_in[17];
    const float* lin2_b  = (const float*)d_in[18];
    float* out = (float*)d_out;

    // ---- workspace layout: 1 MB header + 128 MB buffers = 129 MB total ----
    char* ws = (char*)d_ws;
    const size_t MB = 1ull << 20;
    const size_t BASE = 1 * MB;
    float*          dis  = (float*)(ws + 0);              // 128 KB
    float*          sF   = (float*)(ws + 256 * 1024);     // 40 KB stats
    float*          agg2 = (float*)(ws + BASE);                     // [N,512] fp32: BASE..+64MB
    unsigned short* h2   = (unsigned short*)(ws + BASE + 64 * MB);  // [N,1024] bf16: +64..128MB
    unsigned short* h1   = (unsigned short*)(ws + BASE + 64 * MB);  // [N,512] bf16: +64..96MB (dead before gemm2)
    float*          agg1 = (float*)(ws + BASE + 96 * MB);           // [N,128] fp32: +96..112MB (dead before gemm2)
    // CSR region: +112..115MB — inside h2's span, dead after conv2 gather (clobbered by gemm2's h2 write)
    char*  CSR0     = ws + BASE + 112 * MB;
    int*   csr_src  = (int*)(CSR0);                 // 1 MB
    float* csr_w    = (float*)(CSR0 + 1 * MB);      // 1 MB
    int*   cnt      = (int*)(CSR0 + 2 * MB);        // 128 KB
    int*   offs     = (int*)(CSR0 + 2 * MB + 256 * 1024);   // 128 KB + 4
    int*   cursor   = (int*)(CSR0 + 2 * MB + 512 * 1024);   // 128 KB
    float*          pool = (float*)(ws + BASE);           // [G,1024] fp32 overlays agg2 (dead)
    float*          z    = (float*)(ws + BASE + 4 * MB);  // [G,512] fp32

    float* bn1_sum = sF + 0,      *bn1_sq    = sF + 512;
    float* bn1_scale = sF + 1024, *bn1_shift = sF + 1536;
    float* bn2_sum = sF + 2048,   *bn2_sq    = sF + 3072;
    float* bn2_scale = sF + 4096, *bn2_shift = sF + 5120;
    float* ln1_a = sF + 6144, *ln1_c = sF + 7168;
    float* ln2_a = sF + 8192, *ln2_c = sF + 8704;
    double* lnacc = (double*)(sF + 9216);   // [0,1]=ln1  [2,3]=ln2

    hipMemsetAsync(sF, 0, 40960, stream);
    hipMemsetAsync(cnt, 0, NNODES * 4, stream);

    // ---- CSR build (by dst) + dis ----
    csr_count<<<(NEDGES + 255) / 256, 256, 0, stream>>>(dst, cnt);
    csr_scan<<<1, 1024, 0, stream>>>(cnt, offs, cursor, dis);
    csr_fill<<<(NEDGES + 255) / 256, 256, 0, stream>>>(src, dst, dis, cursor, csr_src, csr_w);

    // ---- conv1: agg1 = A @ x ; h1 = agg1 @ W1 + b1 (bf16) ----
    gcn_gather<FIN, 0><<<NNODES / 4, 256, 0, stream>>>(x, offs, csr_src, csr_w, dis, agg1);
    gemm_f32<0, 1><<<dim3(HID1 / 64, NNODES / 64), 256, 0, stream>>>(agg1, conv1_w, conv1_b, h1, NNODES, HID1, FIN);

    // ---- bn1 + relu ----
    col_stats_b<<<dim3(HID1 / 64, 64), 256, 0, stream>>>(h1, NNODES, HID1, bn1_sum, bn1_sq);
    bn_finalize<<<(HID1 + 255) / 256, 256, 0, stream>>>(bn1_sum, bn1_sq, bn1_w, bn1_b, bn1_scale, bn1_shift, HID1, 1.0f / NNODES);
    bn_apply_b<false><<<2048, 256, 0, stream>>>(h1, bn1_scale, bn1_shift, NNODES * HID1 / 4, HID1 / 4 - 1, nullptr);

    // ---- conv2: agg2 = A @ h1 ; h2 = agg2 @ W2 + b2 (bf16) ----
    gcn_gather<HID1, 1><<<NNODES / 4, 256, 0, stream>>>(h1, offs, csr_src, csr_w, dis, agg2);
    gemm_f32<0, 1><<<dim3(HID2 / 64, NNODES / 64), 256, 0, stream>>>(agg2, conv2_w, conv2_b, h2, NNODES, HID2, HID1);

    // ---- bn2 + relu (+ accumulate LN1 global stats) ----
    col_stats_b<<<dim3(HID2 / 64, 64), 256, 0, stream>>>(h2, NNODES, HID2, bn2_sum, bn2_sq);
    bn_finalize<<<(HID2 + 255) / 256, 256, 0, stream>>>(bn2_sum, bn2_sq, bn2_w, bn2_b, bn2_scale, bn2_shift, HID2, 1.0f / NNODES);
    bn_apply_b<true><<<2048, 256, 0, stream>>>(h2, bn2_scale, bn2_shift, NNODES * HID2 / 4, HID2 / 4 - 1, lnacc);

    // ---- LN1 affine + fused pool ----
    ln_finalize<<<1, HID2, 0, stream>>>(lnacc, ln1_w, ln1_b, ln1_a, ln1_c, HID2, 1.0 / ((double)NNODES * HID2));
    pool_ln_b<<<NGRAPH, 256, 0, stream>>>(h2, ln1_a, ln1_c, pool);

    // ---- lin1 + relu (fp32) ----
    gemm_f32<1, 0><<<dim3(HID1 / 64, NGRAPH / 64), 256, 0, stream>>>(pool, lin1_w, lin1_b, z, NGRAPH, HID1, HID2);

    // ---- LN2 + lin2 + log_softmax ----
    global_stats<<<512, 256, 0, stream>>>(z, NGRAPH * HID1 / 4, lnacc + 2);
    ln_finalize<<<1, HID1, 0, stream>>>(lnacc + 2, ln2_w, ln2_b, ln2_a, ln2_c, HID1, 1.0 / ((double)NGRAPH * HID1));
    gemm4_lsm<<<NGRAPH, 64, 0, stream>>>(z, ln2_a, ln2_c, lin2_w, lin2_b, out);
}

// Round 4
// 601.169 us; speedup vs baseline: 4.9783x; 1.5333x over previous
//
#include <hip/hip_runtime.h>
#include <hip/hip_bf16.h>

#define NNODES 32768
#define NEDGES 262144
#define FIN    128
#define HID1   512
#define HID2   1024
#define NGRAPH 1024
#define NCLS   20

typedef __attribute__((ext_vector_type(8))) short bf16x8;
typedef __attribute__((ext_vector_type(4))) float f32x4;

// ---- bf16 bit helpers (RNE) ----
__device__ inline float bf2f(unsigned short u) {
    union { unsigned int i; float f; } v; v.i = ((unsigned int)u) << 16; return v.f;
}
__device__ inline unsigned short f2bf(float f) {
    union { unsigned int i; float f; } v; v.f = f;
    unsigned int r = v.i + 0x7FFF + ((v.i >> 16) & 1);
    return (unsigned short)(r >> 16);
}

// ================= weight transpose + bf16 convert: Wt[n][k] = bf16(W[k][n]) =================
__global__ __launch_bounds__(256) void wtrans(const float* __restrict__ W,
                                              unsigned short* __restrict__ Wt,
                                              int K, int N) {
    __shared__ unsigned short tile[64][72];
    int kb = blockIdx.y * 64, nb = blockIdx.x * 64;
    {
        int k = threadIdx.x >> 2;
        int n0 = (threadIdx.x & 3) * 16;
#pragma unroll
        for (int q = 0; q < 4; ++q) {
            float4 v = *(const float4*)(W + (size_t)(kb + k) * N + nb + n0 + q * 4);
            tile[k][n0 + q * 4 + 0] = f2bf(v.x);
            tile[k][n0 + q * 4 + 1] = f2bf(v.y);
            tile[k][n0 + q * 4 + 2] = f2bf(v.z);
            tile[k][n0 + q * 4 + 3] = f2bf(v.w);
        }
    }
    __syncthreads();
    {
        int n = threadIdx.x >> 2;
        int k0 = (threadIdx.x & 3) * 16;
#pragma unroll
        for (int q = 0; q < 4; ++q) {
            ushort4 u;
            u.x = tile[k0 + q * 4 + 0][n];
            u.y = tile[k0 + q * 4 + 1][n];
            u.z = tile[k0 + q * 4 + 2][n];
            u.w = tile[k0 + q * 4 + 3][n];
            *(ushort4*)(Wt + (size_t)(nb + n) * K + kb + k0 + q * 4) = u;
        }
    }
}

// ================= CSR build (by dst) =================
__global__ __launch_bounds__(256) void csr_count(const int* __restrict__ dst, int* __restrict__ cnt) {
    int e = blockIdx.x * 256 + threadIdx.x;
    if (e < NEDGES) atomicAdd(&cnt[dst[e]], 1);
}

__global__ __launch_bounds__(1024) void csr_scan(const int* __restrict__ cnt,
                                                 int* __restrict__ offs,
                                                 int* __restrict__ cursor,
                                                 float* __restrict__ dis) {
    __shared__ int part[1024];
    int t = threadIdx.x;
    int base = t * 32;
    int s = 0;
#pragma unroll
    for (int i = 0; i < 32; ++i) s += cnt[base + i];
    part[t] = s;
    __syncthreads();
    for (int off = 1; off < 1024; off <<= 1) {
        int v = (t >= off) ? part[t - off] : 0;
        __syncthreads();
        part[t] += v;
        __syncthreads();
    }
    int run = (t == 0) ? 0 : part[t - 1];
#pragma unroll
    for (int i = 0; i < 32; ++i) {
        int c = cnt[base + i];
        offs[base + i] = run;
        cursor[base + i] = run;
        dis[base + i] = rsqrtf((float)(c + 1));
        run += c;
    }
    if (t == 1023) offs[NNODES] = run;
}

__global__ __launch_bounds__(256) void csr_fill(const int* __restrict__ src,
                                                const int* __restrict__ dst,
                                                const float* __restrict__ dis,
                                                int* __restrict__ cursor,
                                                int* __restrict__ csr_src,
                                                float* __restrict__ csr_w) {
    int e = blockIdx.x * 256 + threadIdx.x;
    if (e >= NEDGES) return;
    int s = src[e], d = dst[e];
    int pos = atomicAdd(&cursor[d], 1);
    csr_src[pos] = s;
    csr_w[pos] = dis[s] * dis[d];
}

// ================= gather aggregation -> bf16 out =================
// one wave per node; lane covers CPL = F/64 channels. BFIN: X is bf16.
template<int F, int BFIN>
__global__ __launch_bounds__(256) void gcn_gather(const void* __restrict__ Xv,
                                                  const int* __restrict__ offs,
                                                  const int* __restrict__ csr_src,
                                                  const float* __restrict__ csr_w,
                                                  const float* __restrict__ dis,
                                                  unsigned short* __restrict__ out) {
    constexpr int CPL = F / 64;          // 2 (F=128) or 8 (F=512)
    int wave = threadIdx.x >> 6, lane = threadIdx.x & 63;
    int node = blockIdx.x * 4 + wave;
    int c0 = lane * CPL;
    float acc[CPL];
    float sw = dis[node]; sw *= sw;

    if (BFIN) {
        const unsigned short* r = (const unsigned short*)Xv + (size_t)node * F + c0;
#pragma unroll
        for (int q = 0; q < (CPL + 3) / 4; ++q) {
            ushort4 u = *(const ushort4*)(r + q * 4);
            acc[q * 4 + 0] = sw * bf2f(u.x);
            acc[q * 4 + 1] = sw * bf2f(u.y);
            acc[q * 4 + 2] = sw * bf2f(u.z);
            acc[q * 4 + 3] = sw * bf2f(u.w);
        }
    } else if (CPL == 2) {
        float2 u = *(const float2*)((const float*)Xv + (size_t)node * F + c0);
        acc[0] = sw * u.x; acc[1] = sw * u.y;
    } else {
#pragma unroll
        for (int q = 0; q < (CPL + 3) / 4; ++q) {
            float4 u = *(const float4*)((const float*)Xv + (size_t)node * F + c0 + q * 4);
            acc[q * 4 + 0] = sw * u.x; acc[q * 4 + 1] = sw * u.y;
            acc[q * 4 + 2] = sw * u.z; acc[q * 4 + 3] = sw * u.w;
        }
    }

    int e0 = offs[node], e1 = offs[node + 1];
    for (int e = e0; e < e1; ++e) {
        int s = csr_src[e];
        float w = csr_w[e];
        if (BFIN) {
            const unsigned short* r = (const unsigned short*)Xv + (size_t)s * F + c0;
#pragma unroll
            for (int q = 0; q < (CPL + 3) / 4; ++q) {
                ushort4 u = *(const ushort4*)(r + q * 4);
                acc[q * 4 + 0] += w * bf2f(u.x);
                acc[q * 4 + 1] += w * bf2f(u.y);
                acc[q * 4 + 2] += w * bf2f(u.z);
                acc[q * 4 + 3] += w * bf2f(u.w);
            }
        } else if (CPL == 2) {
            float2 u = *(const float2*)((const float*)Xv + (size_t)s * F + c0);
            acc[0] += w * u.x; acc[1] += w * u.y;
        } else {
#pragma unroll
            for (int q = 0; q < (CPL + 3) / 4; ++q) {
                float4 u = *(const float4*)((const float*)Xv + (size_t)s * F + c0 + q * 4);
                acc[q * 4 + 0] += w * u.x; acc[q * 4 + 1] += w * u.y;
                acc[q * 4 + 2] += w * u.z; acc[q * 4 + 3] += w * u.w;
            }
        }
    }

    unsigned short* o = out + (size_t)node * F + c0;
    if (CPL == 2) {
        ushort2 u; u.x = f2bf(acc[0]); u.y = f2bf(acc[1]);
        *(ushort2*)o = u;
    } else {
#pragma unroll
        for (int q = 0; q < (CPL + 3) / 4; ++q) {
            ushort4 u;
            u.x = f2bf(acc[q * 4 + 0]); u.y = f2bf(acc[q * 4 + 1]);
            u.z = f2bf(acc[q * 4 + 2]); u.w = f2bf(acc[q * 4 + 3]);
            *(ushort4*)(o + q * 4) = u;
        }
    }
}

// ================= bf16 MFMA GEMM: C[M][N] = A[M][K] @ B, with Bt[N][K] =================
// 128x128 tile, BK=64, 4 waves (each a 64x64 quadrant, 4x4 frags of 16x16x32).
// LDS XOR-swizzle sub^=(row&7)<<4 on write and read (2-way conflicts = free).
// EPI=1: relu. CBF16=1: store bf16, else f32.
template<int EPI, int CBF16>
__global__ __launch_bounds__(256) void gemm_mfma(const unsigned short* __restrict__ A,
                                                 const unsigned short* __restrict__ Bt,
                                                 const float* __restrict__ bias,
                                                 void* __restrict__ Cv,
                                                 int M, int N, int K) {
    constexpr int BM = 128, BN = 128, BK = 64;
    __shared__ unsigned short As[BM * BK];   // [128][64] bf16, 128B rows
    __shared__ unsigned short Bs[BN * BK];
    const int tid = threadIdx.x;
    const int lane = tid & 63;
    const int wave = tid >> 6;
    const int wr = wave >> 1, wc = wave & 1;
    const int m0 = blockIdx.y * BM, n0 = blockIdx.x * BN;

    f32x4 acc[4][4] = {};

    for (int k0 = 0; k0 < K; k0 += BK) {
        int4 av[4], bv[4];
#pragma unroll
        for (int i = 0; i < 4; ++i) {
            int off = (tid + 256 * i) * 16;          // byte offset in 16KB tile
            int r = off >> 7, sub = off & 127;       // row, byte-in-row
            av[i] = *(const int4*)((const char*)A + ((size_t)(m0 + r) * K + k0) * 2 + sub);
            bv[i] = *(const int4*)((const char*)Bt + ((size_t)(n0 + r) * K + k0) * 2 + sub);
        }
        __syncthreads();   // previous iteration's LDS reads complete
#pragma unroll
        for (int i = 0; i < 4; ++i) {
            int off = (tid + 256 * i) * 16;
            int r = off >> 7, sub = off & 127;
            int subsw = sub ^ ((r & 7) << 4);
            *(int4*)((char*)As + r * 128 + subsw) = av[i];
            *(int4*)((char*)Bs + r * 128 + subsw) = bv[i];
        }
        __syncthreads();
#pragma unroll
        for (int ks = 0; ks < 2; ++ks) {
            bf16x8 af[4], bfr[4];
#pragma unroll
            for (int m = 0; m < 4; ++m) {
                int row = wr * 64 + m * 16 + (lane & 15);
                int sub = (ks * 64 + ((lane >> 4) * 16)) ^ ((row & 7) << 4);
                af[m] = *(const bf16x8*)((const char*)As + row * 128 + sub);
            }
#pragma unroll
            for (int n = 0; n < 4; ++n) {
                int row = wc * 64 + n * 16 + (lane & 15);
                int sub = (ks * 64 + ((lane >> 4) * 16)) ^ ((row & 7) << 4);
                bfr[n] = *(const bf16x8*)((const char*)Bs + row * 128 + sub);
            }
#pragma unroll
            for (int m = 0; m < 4; ++m)
#pragma unroll
                for (int n = 0; n < 4; ++n)
                    acc[m][n] = __builtin_amdgcn_mfma_f32_16x16x32_bf16(af[m], bfr[n], acc[m][n], 0, 0, 0);
        }
    }

    // epilogue: C row = m0 + wr*64 + m*16 + (lane>>4)*4 + j ; col = n0 + wc*64 + n*16 + (lane&15)
#pragma unroll
    for (int m = 0; m < 4; ++m) {
        int row = m0 + wr * 64 + m * 16 + ((lane >> 4) << 2);
#pragma unroll
        for (int n = 0; n < 4; ++n) {
            int col = n0 + wc * 64 + n * 16 + (lane & 15);
            float bsv = bias[col];
#pragma unroll
            for (int j = 0; j < 4; ++j) {
                float v = acc[m][n][j] + bsv;
                if (EPI == 1) v = fmaxf(v, 0.f);
                if (CBF16) ((unsigned short*)Cv)[(size_t)(row + j) * N + col] = f2bf(v);
                else       ((float*)Cv)[(size_t)(row + j) * N + col] = v;
            }
        }
    }
}

// ---------------- per-column (BatchNorm) stats over bf16 ----------------
__global__ __launch_bounds__(256) void col_stats_b(const unsigned short* __restrict__ X,
                                                   int rows, int cols,
                                                   float* __restrict__ sum, float* __restrict__ sumsq) {
    int col = blockIdx.x * 64 + (threadIdx.x & 63);
    int yt = threadIdx.x >> 6;
    int rowsPer = rows / (gridDim.y * 4);
    int r0 = (blockIdx.y * 4 + yt) * rowsPer;
    float s = 0.f, ss = 0.f;
    for (int r = r0; r < r0 + rowsPer; ++r) {
        float v = bf2f(X[(size_t)r * cols + col]);
        s += v; ss += v * v;
    }
    atomicAdd(&sum[col], s);
    atomicAdd(&sumsq[col], ss);
}

__global__ void bn_finalize(const float* __restrict__ sum, const float* __restrict__ sq,
                            const float* __restrict__ w, const float* __restrict__ b,
                            float* __restrict__ scale, float* __restrict__ shift,
                            int cols, float invN) {
    int c = blockIdx.x * blockDim.x + threadIdx.x;
    if (c >= cols) return;
    float mu = sum[c] * invN;
    float var = sq[c] * invN - mu * mu;
    float sc = rsqrtf(var + 1e-5f) * w[c];
    scale[c] = sc;
    shift[c] = b[c] - mu * sc;
}

// ---------------- BN apply + ReLU on bf16 (optionally accumulate global LN stats) ----------------
template<bool LNACC>
__global__ __launch_bounds__(256) void bn_apply_b(unsigned short* __restrict__ X,
                                                  const float* __restrict__ scale,
                                                  const float* __restrict__ shift,
                                                  int total4, int c4mask, double* lnacc) {
    float lsum = 0.f, lsq = 0.f;
    for (int t = blockIdx.x * 256 + threadIdx.x; t < total4; t += gridDim.x * 256) {
        int c4 = (t & c4mask) * 4;
        ushort4 u = ((ushort4*)X)[t];
        float4 sc = *(const float4*)(scale + c4);
        float4 sh = *(const float4*)(shift + c4);
        float4 v;
        v.x = fmaxf(bf2f(u.x) * sc.x + sh.x, 0.f);
        v.y = fmaxf(bf2f(u.y) * sc.y + sh.y, 0.f);
        v.z = fmaxf(bf2f(u.z) * sc.z + sh.z, 0.f);
        v.w = fmaxf(bf2f(u.w) * sc.w + sh.w, 0.f);
        u.x = f2bf(v.x); u.y = f2bf(v.y); u.z = f2bf(v.z); u.w = f2bf(v.w);
        ((ushort4*)X)[t] = u;
        if (LNACC) {
            float a = bf2f(u.x), b = bf2f(u.y), c = bf2f(u.z), d = bf2f(u.w);
            lsum += a + b + c + d;
            lsq  += a * a + b * b + c * c + d * d;
        }
    }
    if (LNACC) {
        for (int o = 32; o > 0; o >>= 1) {
            lsum += __shfl_down(lsum, o);
            lsq  += __shfl_down(lsq, o);
        }
        __shared__ float w1[4], w2[4];
        int wid = threadIdx.x >> 6, lane = threadIdx.x & 63;
        if (lane == 0) { w1[wid] = lsum; w2[wid] = lsq; }
        __syncthreads();
        if (threadIdx.x == 0) {
            atomicAdd(lnacc,     (double)(w1[0] + w1[1] + w1[2] + w1[3]));
            atomicAdd(lnacc + 1, (double)(w2[0] + w2[1] + w2[2] + w2[3]));
        }
    }
}

// ---------------- global stats (LN2 over z, fp32) ----------------
__global__ __launch_bounds__(256) void global_stats(const float* __restrict__ X, int total4, double* acc) {
    float s = 0.f, ss = 0.f;
    for (int t = blockIdx.x * 256 + threadIdx.x; t < total4; t += gridDim.x * 256) {
        float4 v = ((const float4*)X)[t];
        s  += v.x + v.y + v.z + v.w;
        ss += v.x * v.x + v.y * v.y + v.z * v.z + v.w * v.w;
    }
    for (int o = 32; o > 0; o >>= 1) {
        s += __shfl_down(s, o);
        ss += __shfl_down(ss, o);
    }
    __shared__ float w1[4], w2[4];
    int wid = threadIdx.x >> 6, lane = threadIdx.x & 63;
    if (lane == 0) { w1[wid] = s; w2[wid] = ss; }
    __syncthreads();
    if (threadIdx.x == 0) {
        atomicAdd(acc,     (double)(w1[0] + w1[1] + w1[2] + w1[3]));
        atomicAdd(acc + 1, (double)(w2[0] + w2[1] + w2[2] + w2[3]));
    }
}

// ---------------- LN finalize: per-channel affine a[c], c[c] ----------------
__global__ void ln_finalize(const double* __restrict__ acc, const float* __restrict__ w,
                            const float* __restrict__ b, float* __restrict__ a,
                            float* __restrict__ c, int cols, double invCount) {
    __shared__ float smu, sinv;
    if (threadIdx.x == 0) {
        double mu  = acc[0] * invCount;
        double var = acc[1] * invCount - mu * mu;
        if (var < 0.0) var = 0.0;
        float stdv = sqrtf((float)var);
        smu = (float)mu;
        sinv = 1.0f / (stdv + 1e-5f);
    }
    __syncthreads();
    int ci = threadIdx.x;
    if (ci < cols) {
        float A = sinv * w[ci];
        a[ci] = A;
        c[ci] = b[ci] - smu * A;
    }
}

// ---------------- fused LN + per-graph max pool -> bf16 ----------------
__global__ __launch_bounds__(256) void pool_ln_b(const unsigned short* __restrict__ H,
                                                 const float* __restrict__ a,
                                                 const float* __restrict__ c,
                                                 unsigned short* __restrict__ P) {
    int g = blockIdx.x;
    int c0 = threadIdx.x * 4;
    float4 av = *(const float4*)(a + c0);
    float4 cv = *(const float4*)(c + c0);
    float4 m = make_float4(-1e30f, -1e30f, -1e30f, -1e30f);
    const unsigned short* row = H + (size_t)g * 32 * HID2 + c0;
    for (int n = 0; n < 32; ++n, row += HID2) {
        ushort4 u = *(const ushort4*)row;
        m.x = fmaxf(m.x, bf2f(u.x) * av.x + cv.x);
        m.y = fmaxf(m.y, bf2f(u.y) * av.y + cv.y);
        m.z = fmaxf(m.z, bf2f(u.z) * av.z + cv.z);
        m.w = fmaxf(m.w, bf2f(u.w) * av.w + cv.w);
    }
    ushort4 o;
    o.x = f2bf(m.x); o.y = f2bf(m.y); o.z = f2bf(m.z); o.w = f2bf(m.w);
    *(ushort4*)(P + (size_t)g * HID2 + c0) = o;
}

// ---------------- fused LN2 + final GEMM [1024,512]@[512,20] + log_softmax ----------------
__global__ __launch_bounds__(64) void gemm4_lsm(const float* __restrict__ Z,
                                                const float* __restrict__ a,
                                                const float* __restrict__ c,
                                                const float* __restrict__ W,
                                                const float* __restrict__ bias,
                                                float* __restrict__ out) {
    __shared__ float zs[HID1];
    __shared__ float logits[NCLS];
    __shared__ float smax, slse;
    int m = blockIdx.x;
    for (int k = threadIdx.x; k < HID1; k += 64)
        zs[k] = Z[(size_t)m * HID1 + k] * a[k] + c[k];
    __syncthreads();
    if (threadIdx.x < NCLS) {
        float acc = bias[threadIdx.x];
        for (int k = 0; k < HID1; ++k)
            acc += zs[k] * W[k * NCLS + threadIdx.x];
        logits[threadIdx.x] = acc;
    }
    __syncthreads();
    if (threadIdx.x == 0) {
        float mx = -1e30f;
        for (int j = 0; j < NCLS; ++j) mx = fmaxf(mx, logits[j]);
        float s = 0.f;
        for (int j = 0; j < NCLS; ++j) s += expf(logits[j] - mx);
        smax = mx; slse = logf(s);
    }
    __syncthreads();
    if (threadIdx.x < NCLS)
        out[(size_t)m * NCLS + threadIdx.x] = logits[threadIdx.x] - smax - slse;
}

// ======================== launch ========================
extern "C" void kernel_launch(void* const* d_in, const int* in_sizes, int n_in,
                              void* d_out, int out_size, void* d_ws, size_t ws_size,
                              hipStream_t stream) {
    const float* x       = (const float*)d_in[0];
    const int*   ei      = (const int*)d_in[1];
    const int*   src     = ei;
    const int*   dst     = ei + NEDGES;
    const float* conv1_w = (const float*)d_in[3];
    const float* conv1_b = (const float*)d_in[4];
    const float* bn1_w   = (const float*)d_in[5];
    const float* bn1_b   = (const float*)d_in[6];
    const float* conv2_w = (const float*)d_in[7];
    const float* conv2_b = (const float*)d_in[8];
    const float* bn2_w   = (const float*)d_in[9];
    const float* bn2_b   = (const float*)d_in[10];
    const float* ln1_w   = (const float*)d_in[11];
    const float* ln1_b   = (const float*)d_in[12];
    const float* lin1_w  = (const float*)d_in[13];
    const float* lin1_b  = (const float*)d_in[14];
    const float* ln2_w   = (const float*)d_in[15];
    const float* ln2_b   = (const float*)d_in[16];
    const float* lin2_w  = (const float*)d_in[17];
    const float* lin2_b  = (const float*)d_in[18];
    float* out = (float*)d_out;

    // ---- workspace layout (peak 120 MB) ----
    char* ws = (char*)d_ws;
    const size_t KB = 1024, MB = 1048576;
    float*          dis     = (float*)(ws + 0);            // 128K
    float*          sF      = (float*)(ws + 128 * KB);     // 64K stats
    unsigned short* w1t     = (unsigned short*)(ws + 256 * KB);   // [512][128]  128K
    unsigned short* w2t     = (unsigned short*)(ws + 512 * KB);   // [1024][512] 1M
    unsigned short* w3t     = (unsigned short*)(ws + 1536 * KB);  // [512][1024] 1M
    int*            cnt     = (int*)(ws + 2560 * KB);      // 128K
    int*            offs    = (int*)(ws + 2688 * KB);      // 128K+4 (192K reserved)
    int*            cursor  = (int*)(ws + 2880 * KB);      // 128K
    int*            csr_src = (int*)(ws + 3 * MB);         // 1M
    float*          csr_w   = (float*)(ws + 4 * MB);       // 1M
    unsigned short* pool    = (unsigned short*)(ws + 5 * MB);   // [1024][1024] bf16 2M
    float*          z       = (float*)(ws + 7 * MB);       // [1024][512] f32 2M
    unsigned short* agg1    = (unsigned short*)(ws + 16 * MB);  // [N,128] bf16 8M   (16-24)
    unsigned short* h1      = (unsigned short*)(ws + 24 * MB);  // [N,512] bf16 32M  (24-56)
    unsigned short* h2      = (unsigned short*)(ws + 16 * MB);  // [N,1024] bf16 64M (16-80, overlays dead agg1+h1)
    unsigned short* agg2    = (unsigned short*)(ws + 88 * MB);  // [N,512] bf16 32M  (88-120)

    float* bn1_sum = sF + 0,      *bn1_sq    = sF + 512;
    float* bn1_scale = sF + 1024, *bn1_shift = sF + 1536;
    float* bn2_sum = sF + 2048,   *bn2_sq    = sF + 3072;
    float* bn2_scale = sF + 4096, *bn2_shift = sF + 5120;
    float* ln1_a = sF + 6144, *ln1_c = sF + 7168;
    float* ln2_a = sF + 8192, *ln2_c = sF + 8704;
    double* lnacc = (double*)(sF + 9216);   // [0,1]=ln1  [2,3]=ln2

    hipMemsetAsync(sF, 0, 40960, stream);
    hipMemsetAsync(cnt, 0, NNODES * 4, stream);

    // ---- weight transposes (bf16) ----
    wtrans<<<dim3(HID1 / 64, FIN / 64),  256, 0, stream>>>(conv1_w, w1t, FIN, HID1);
    wtrans<<<dim3(HID2 / 64, HID1 / 64), 256, 0, stream>>>(conv2_w, w2t, HID1, HID2);
    wtrans<<<dim3(HID1 / 64, HID2 / 64), 256, 0, stream>>>(lin1_w,  w3t, HID2, HID1);

    // ---- CSR build (by dst) + dis ----
    csr_count<<<(NEDGES + 255) / 256, 256, 0, stream>>>(dst, cnt);
    csr_scan<<<1, 1024, 0, stream>>>(cnt, offs, cursor, dis);
    csr_fill<<<(NEDGES + 255) / 256, 256, 0, stream>>>(src, dst, dis, cursor, csr_src, csr_w);

    // ---- conv1: agg1 = A @ x ; h1 = agg1 @ W1 + b1 ----
    gcn_gather<FIN, 0><<<NNODES / 4, 256, 0, stream>>>(x, offs, csr_src, csr_w, dis, agg1);
    gemm_mfma<0, 1><<<dim3(HID1 / 128, NNODES / 128), 256, 0, stream>>>(agg1, w1t, conv1_b, h1, NNODES, HID1, FIN);

    // ---- bn1 + relu ----
    col_stats_b<<<dim3(HID1 / 64, 64), 256, 0, stream>>>(h1, NNODES, HID1, bn1_sum, bn1_sq);
    bn_finalize<<<(HID1 + 255) / 256, 256, 0, stream>>>(bn1_sum, bn1_sq, bn1_w, bn1_b, bn1_scale, bn1_shift, HID1, 1.0f / NNODES);
    bn_apply_b<false><<<2048, 256, 0, stream>>>(h1, bn1_scale, bn1_shift, NNODES * HID1 / 4, HID1 / 4 - 1, nullptr);

    // ---- conv2: agg2 = A @ h1 ; h2 = agg2 @ W2 + b2 ----
    gcn_gather<HID1, 1><<<NNODES / 4, 256, 0, stream>>>(h1, offs, csr_src, csr_w, dis, agg2);
    gemm_mfma<0, 1><<<dim3(HID2 / 128, NNODES / 128), 256, 0, stream>>>(agg2, w2t, conv2_b, h2, NNODES, HID2, HID1);

    // ---- bn2 + relu (+ LN1 global stats) ----
    col_stats_b<<<dim3(HID2 / 64, 64), 256, 0, stream>>>(h2, NNODES, HID2, bn2_sum, bn2_sq);
    bn_finalize<<<(HID2 + 255) / 256, 256, 0, stream>>>(bn2_sum, bn2_sq, bn2_w, bn2_b, bn2_scale, bn2_shift, HID2, 1.0f / NNODES);
    bn_apply_b<true><<<2048, 256, 0, stream>>>(h2, bn2_scale, bn2_shift, NNODES * HID2 / 4, HID2 / 4 - 1, lnacc);

    // ---- LN1 affine + fused pool (bf16 out) ----
    ln_finalize<<<1, HID2, 0, stream>>>(lnacc, ln1_w, ln1_b, ln1_a, ln1_c, HID2, 1.0 / ((double)NNODES * HID2));
    pool_ln_b<<<NGRAPH, 256, 0, stream>>>(h2, ln1_a, ln1_c, pool);

    // ---- lin1 + relu (MFMA, f32 out) ----
    gemm_mfma<1, 0><<<dim3(HID1 / 128, NGRAPH / 128), 256, 0, stream>>>(pool, w3t, lin1_b, z, NGRAPH, HID1, HID2);

    // ---- LN2 + lin2 + log_softmax ----
    global_stats<<<512, 256, 0, stream>>>(z, NGRAPH * HID1 / 4, lnacc + 2);
    ln_finalize<<<1, HID1, 0, stream>>>(lnacc + 2, ln2_w, ln2_b, ln2_a, ln2_c, HID1, 1.0 / ((double)NGRAPH * HID1));
    gemm4_lsm<<<NGRAPH, 64, 0, stream>>>(z, ln2_a, ln2_c, lin2_w, lin2_b, out);
}

// Round 5
// 508.201 us; speedup vs baseline: 5.8890x; 1.1829x over previous
//
#include <hip/hip_runtime.h>
#include <hip/hip_bf16.h>

#define NNODES 32768
#define NEDGES 262144
#define FIN    128
#define HID1   512
#define HID2   1024
#define NGRAPH 1024
#define NCLS   20

typedef __attribute__((ext_vector_type(8))) short bf16x8;
typedef __attribute__((ext_vector_type(4))) float f32x4;

// ---- bf16 bit helpers (RNE) ----
__device__ inline float bf2f(unsigned short u) {
    union { unsigned int i; float f; } v; v.i = ((unsigned int)u) << 16; return v.f;
}
__device__ inline unsigned short f2bf(float f) {
    union { unsigned int i; float f; } v; v.f = f;
    unsigned int r = v.i + 0x7FFF + ((v.i >> 16) & 1);
    return (unsigned short)(r >> 16);
}

// ================= weight transpose + bf16 convert: Wt[n][k] = bf16(W[k][n]) =================
__global__ __launch_bounds__(256) void wtrans(const float* __restrict__ W,
                                              unsigned short* __restrict__ Wt,
                                              int K, int N) {
    __shared__ unsigned short tile[64][72];
    int kb = blockIdx.y * 64, nb = blockIdx.x * 64;
    {
        int k = threadIdx.x >> 2;
        int n0 = (threadIdx.x & 3) * 16;
#pragma unroll
        for (int q = 0; q < 4; ++q) {
            float4 v = *(const float4*)(W + (size_t)(kb + k) * N + nb + n0 + q * 4);
            tile[k][n0 + q * 4 + 0] = f2bf(v.x);
            tile[k][n0 + q * 4 + 1] = f2bf(v.y);
            tile[k][n0 + q * 4 + 2] = f2bf(v.z);
            tile[k][n0 + q * 4 + 3] = f2bf(v.w);
        }
    }
    __syncthreads();
    {
        int n = threadIdx.x >> 2;
        int k0 = (threadIdx.x & 3) * 16;
#pragma unroll
        for (int q = 0; q < 4; ++q) {
            ushort4 u;
            u.x = tile[k0 + q * 4 + 0][n];
            u.y = tile[k0 + q * 4 + 1][n];
            u.z = tile[k0 + q * 4 + 2][n];
            u.w = tile[k0 + q * 4 + 3][n];
            *(ushort4*)(Wt + (size_t)(nb + n) * K + kb + k0 + q * 4) = u;
        }
    }
}

// ================= CSR build (by dst) =================
__global__ __launch_bounds__(256) void csr_count(const int* __restrict__ dst, int* __restrict__ cnt) {
    int e = blockIdx.x * 256 + threadIdx.x;
    if (e < NEDGES) atomicAdd(&cnt[dst[e]], 1);
}

__global__ __launch_bounds__(1024) void csr_scan(const int* __restrict__ cnt,
                                                 int* __restrict__ offs,
                                                 int* __restrict__ cursor,
                                                 float* __restrict__ dis) {
    __shared__ int part[1024];
    int t = threadIdx.x;
    int base = t * 32;
    int s = 0;
#pragma unroll
    for (int i = 0; i < 32; ++i) s += cnt[base + i];
    part[t] = s;
    __syncthreads();
    for (int off = 1; off < 1024; off <<= 1) {
        int v = (t >= off) ? part[t - off] : 0;
        __syncthreads();
        part[t] += v;
        __syncthreads();
    }
    int run = (t == 0) ? 0 : part[t - 1];
#pragma unroll
    for (int i = 0; i < 32; ++i) {
        int c = cnt[base + i];
        offs[base + i] = run;
        cursor[base + i] = run;
        dis[base + i] = rsqrtf((float)(c + 1));
        run += c;
    }
    if (t == 1023) offs[NNODES] = run;
}

__global__ __launch_bounds__(256) void csr_fill(const int* __restrict__ src,
                                                const int* __restrict__ dst,
                                                const float* __restrict__ dis,
                                                int* __restrict__ cursor,
                                                int* __restrict__ csr_src,
                                                float* __restrict__ csr_w) {
    int e = blockIdx.x * 256 + threadIdx.x;
    if (e >= NEDGES) return;
    int s = src[e], d = dst[e];
    int pos = atomicAdd(&cursor[d], 1);
    csr_src[pos] = s;
    csr_w[pos] = dis[s] * dis[d];
}

// ================= gather aggregation -> bf16 out =================
template<int F, int BFIN>
__global__ __launch_bounds__(256) void gcn_gather(const void* __restrict__ Xv,
                                                  const int* __restrict__ offs,
                                                  const int* __restrict__ csr_src,
                                                  const float* __restrict__ csr_w,
                                                  const float* __restrict__ dis,
                                                  unsigned short* __restrict__ out) {
    constexpr int CPL = F / 64;          // 2 (F=128) or 8 (F=512)
    int wave = threadIdx.x >> 6, lane = threadIdx.x & 63;
    int node = blockIdx.x * 4 + wave;
    int c0 = lane * CPL;
    float acc[CPL];
    float sw = dis[node]; sw *= sw;

    if (BFIN) {
        const unsigned short* r = (const unsigned short*)Xv + (size_t)node * F + c0;
#pragma unroll
        for (int q = 0; q < (CPL + 3) / 4; ++q) {
            ushort4 u = *(const ushort4*)(r + q * 4);
            acc[q * 4 + 0] = sw * bf2f(u.x);
            acc[q * 4 + 1] = sw * bf2f(u.y);
            acc[q * 4 + 2] = sw * bf2f(u.z);
            acc[q * 4 + 3] = sw * bf2f(u.w);
        }
    } else if (CPL == 2) {
        float2 u = *(const float2*)((const float*)Xv + (size_t)node * F + c0);
        acc[0] = sw * u.x; acc[1] = sw * u.y;
    } else {
#pragma unroll
        for (int q = 0; q < (CPL + 3) / 4; ++q) {
            float4 u = *(const float4*)((const float*)Xv + (size_t)node * F + c0 + q * 4);
            acc[q * 4 + 0] = sw * u.x; acc[q * 4 + 1] = sw * u.y;
            acc[q * 4 + 2] = sw * u.z; acc[q * 4 + 3] = sw * u.w;
        }
    }

    int e0 = offs[node], e1 = offs[node + 1];
    for (int e = e0; e < e1; ++e) {
        int s = csr_src[e];
        float w = csr_w[e];
        if (BFIN) {
            const unsigned short* r = (const unsigned short*)Xv + (size_t)s * F + c0;
#pragma unroll
            for (int q = 0; q < (CPL + 3) / 4; ++q) {
                ushort4 u = *(const ushort4*)(r + q * 4);
                acc[q * 4 + 0] += w * bf2f(u.x);
                acc[q * 4 + 1] += w * bf2f(u.y);
                acc[q * 4 + 2] += w * bf2f(u.z);
                acc[q * 4 + 3] += w * bf2f(u.w);
            }
        } else if (CPL == 2) {
            float2 u = *(const float2*)((const float*)Xv + (size_t)s * F + c0);
            acc[0] += w * u.x; acc[1] += w * u.y;
        } else {
#pragma unroll
            for (int q = 0; q < (CPL + 3) / 4; ++q) {
                float4 u = *(const float4*)((const float*)Xv + (size_t)s * F + c0 + q * 4);
                acc[q * 4 + 0] += w * u.x; acc[q * 4 + 1] += w * u.y;
                acc[q * 4 + 2] += w * u.z; acc[q * 4 + 3] += w * u.w;
            }
        }
    }

    unsigned short* o = out + (size_t)node * F + c0;
    if (CPL == 2) {
        ushort2 u; u.x = f2bf(acc[0]); u.y = f2bf(acc[1]);
        *(ushort2*)o = u;
    } else {
#pragma unroll
        for (int q = 0; q < (CPL + 3) / 4; ++q) {
            ushort4 u;
            u.x = f2bf(acc[q * 4 + 0]); u.y = f2bf(acc[q * 4 + 1]);
            u.z = f2bf(acc[q * 4 + 2]); u.w = f2bf(acc[q * 4 + 3]);
            *(ushort4*)(o + q * 4) = u;
        }
    }
}

// ================= bf16 MFMA GEMM: C[M][N] = A[M][K] @ B (Bt[N][K]) =================
// 128x128 tile, BK=64, 4 waves. XCD-bijective block swizzle. LDS XOR-swizzle on A/B.
// CBF16=1: LDS-staged coalesced bf16 store. STATS=1: fused per-column sum/sumsq atomics.
// EPI=1: relu (f32 path only).
template<int EPI, int CBF16, int STATS>
__global__ __launch_bounds__(256) void gemm_mfma(const unsigned short* __restrict__ A,
                                                 const unsigned short* __restrict__ Bt,
                                                 const float* __restrict__ bias,
                                                 void* __restrict__ Cv,
                                                 float* __restrict__ gsum,
                                                 float* __restrict__ gsq,
                                                 int M, int N, int K) {
    constexpr int BM = 128, BN = 128, BK = 64;
    __shared__ unsigned short smem[128 * 136];   // K-loop: As[0..8191], Bs[8192..16383]; epilogue: C tile 128x136
    unsigned short* As = smem;
    unsigned short* Bs = smem + BM * BK;

    const int tid = threadIdx.x;
    const int lane = tid & 63;
    const int wave = tid >> 6;
    const int wr = wave >> 1, wc = wave & 1;

    // XCD-bijective swizzle (nwg % 8 == 0 for all our grids)
    const int nwg = gridDim.x * gridDim.y;
    const int wg = blockIdx.y * gridDim.x + blockIdx.x;
    const int cpx = nwg >> 3;
    const int swz = (wg & 7) * cpx + (wg >> 3);
    const int m0 = (swz / gridDim.x) * BM, n0 = (swz % gridDim.x) * BN;

    f32x4 acc[4][4] = {};

    for (int k0 = 0; k0 < K; k0 += BK) {
        int4 av[4], bv[4];
#pragma unroll
        for (int i = 0; i < 4; ++i) {
            int off = (tid + 256 * i) * 16;          // byte offset in 16KB tile
            int r = off >> 7, sub = off & 127;       // row, byte-in-row
            av[i] = *(const int4*)((const char*)A + ((size_t)(m0 + r) * K + k0) * 2 + sub);
            bv[i] = *(const int4*)((const char*)Bt + ((size_t)(n0 + r) * K + k0) * 2 + sub);
        }
        __syncthreads();   // previous iteration's LDS reads complete
#pragma unroll
        for (int i = 0; i < 4; ++i) {
            int off = (tid + 256 * i) * 16;
            int r = off >> 7, sub = off & 127;
            int subsw = sub ^ ((r & 7) << 4);
            *(int4*)((char*)As + r * 128 + subsw) = av[i];
            *(int4*)((char*)Bs + r * 128 + subsw) = bv[i];
        }
        __syncthreads();
#pragma unroll
        for (int ks = 0; ks < 2; ++ks) {
            bf16x8 af[4], bfr[4];
#pragma unroll
            for (int m = 0; m < 4; ++m) {
                int row = wr * 64 + m * 16 + (lane & 15);
                int sub = (ks * 64 + ((lane >> 4) * 16)) ^ ((row & 7) << 4);
                af[m] = *(const bf16x8*)((const char*)As + row * 128 + sub);
            }
#pragma unroll
            for (int n = 0; n < 4; ++n) {
                int row = wc * 64 + n * 16 + (lane & 15);
                int sub = (ks * 64 + ((lane >> 4) * 16)) ^ ((row & 7) << 4);
                bfr[n] = *(const bf16x8*)((const char*)Bs + row * 128 + sub);
            }
#pragma unroll
            for (int m = 0; m < 4; ++m)
#pragma unroll
                for (int n = 0; n < 4; ++n)
                    acc[m][n] = __builtin_amdgcn_mfma_f32_16x16x32_bf16(af[m], bfr[n], acc[m][n], 0, 0, 0);
        }
    }

    // ---- epilogue ----
    // C fragment mapping: row = wr*64 + m*16 + (lane>>4)*4 + j ; col = wc*64 + n*16 + (lane&15)
    if (CBF16) {
        __syncthreads();                         // MFMA LDS reads done; reuse smem for C tile
        float cs[4], cq[4];
#pragma unroll
        for (int n = 0; n < 4; ++n) { cs[n] = 0.f; cq[n] = 0.f; }
#pragma unroll
        for (int n = 0; n < 4; ++n) {
            int col = wc * 64 + n * 16 + (lane & 15);
            float bsv = bias[n0 + col];
#pragma unroll
            for (int m = 0; m < 4; ++m) {
                int rbase = wr * 64 + m * 16 + ((lane >> 4) << 2);
#pragma unroll
                for (int j = 0; j < 4; ++j) {
                    float v = acc[m][n][j] + bsv;
                    if (STATS) { cs[n] += v; cq[n] += v * v; }
                    if (EPI == 1) v = fmaxf(v, 0.f);
                    smem[(rbase + j) * 136 + col] = f2bf(v);
                }
            }
        }
        if (STATS) {
#pragma unroll
            for (int n = 0; n < 4; ++n) {
                cs[n] += __shfl_xor(cs[n], 16); cs[n] += __shfl_xor(cs[n], 32);
                cq[n] += __shfl_xor(cq[n], 16); cq[n] += __shfl_xor(cq[n], 32);
            }
            if (lane < 16) {
#pragma unroll
                for (int n = 0; n < 4; ++n) {
                    int col = n0 + wc * 64 + n * 16 + lane;
                    atomicAdd(&gsum[col], cs[n]);
                    atomicAdd(&gsq[col],  cq[n]);
                }
            }
        }
        __syncthreads();
        // coalesced store: 16 rows x 16 chunks of 16B per iteration
#pragma unroll
        for (int it = 0; it < 8; ++it) {
            int r = it * 16 + (tid >> 4);
            int ch = tid & 15;
            int4 v = *(const int4*)&smem[r * 136 + ch * 8];
            *(int4*)((unsigned short*)Cv + (size_t)(m0 + r) * N + n0 + ch * 8) = v;
        }
    } else {
#pragma unroll
        for (int m = 0; m < 4; ++m) {
            int row = m0 + wr * 64 + m * 16 + ((lane >> 4) << 2);
#pragma unroll
            for (int n = 0; n < 4; ++n) {
                int col = n0 + wc * 64 + n * 16 + (lane & 15);
                float bsv = bias[col];
#pragma unroll
                for (int j = 0; j < 4; ++j) {
                    float v = acc[m][n][j] + bsv;
                    if (EPI == 1) v = fmaxf(v, 0.f);
                    ((float*)Cv)[(size_t)(row + j) * N + col] = v;
                }
            }
        }
    }
}

__global__ void bn_finalize(const float* __restrict__ sum, const float* __restrict__ sq,
                            const float* __restrict__ w, const float* __restrict__ b,
                            float* __restrict__ scale, float* __restrict__ shift,
                            int cols, float invN) {
    int c = blockIdx.x * blockDim.x + threadIdx.x;
    if (c >= cols) return;
    float mu = sum[c] * invN;
    float var = sq[c] * invN - mu * mu;
    float sc = rsqrtf(var + 1e-5f) * w[c];
    scale[c] = sc;
    shift[c] = b[c] - mu * sc;
}

// ---------------- BN apply + ReLU on bf16, in place (h1) ----------------
__global__ __launch_bounds__(256) void bn_apply_b(unsigned short* __restrict__ X,
                                                  const float* __restrict__ scale,
                                                  const float* __restrict__ shift,
                                                  int total4, int c4mask) {
    for (int t = blockIdx.x * 256 + threadIdx.x; t < total4; t += gridDim.x * 256) {
        int c4 = (t & c4mask) * 4;
        ushort4 u = ((ushort4*)X)[t];
        float4 sc = *(const float4*)(scale + c4);
        float4 sh = *(const float4*)(shift + c4);
        u.x = f2bf(fmaxf(bf2f(u.x) * sc.x + sh.x, 0.f));
        u.y = f2bf(fmaxf(bf2f(u.y) * sc.y + sh.y, 0.f));
        u.z = f2bf(fmaxf(bf2f(u.z) * sc.z + sh.z, 0.f));
        u.w = f2bf(fmaxf(bf2f(u.w) * sc.w + sh.w, 0.f));
        ((ushort4*)X)[t] = u;
    }
}

// ---------------- read-only: LN stats of relu(bn(h2)) ----------------
__global__ __launch_bounds__(256) void bn_lnstats(const unsigned short* __restrict__ X,
                                                  const float* __restrict__ scale,
                                                  const float* __restrict__ shift,
                                                  int total4, int c4mask, double* lnacc) {
    float lsum = 0.f, lsq = 0.f;
    for (int t = blockIdx.x * 256 + threadIdx.x; t < total4; t += gridDim.x * 256) {
        int c4 = (t & c4mask) * 4;
        ushort4 u = ((const ushort4*)X)[t];
        float4 sc = *(const float4*)(scale + c4);
        float4 sh = *(const float4*)(shift + c4);
        float a = fmaxf(bf2f(u.x) * sc.x + sh.x, 0.f);
        float b = fmaxf(bf2f(u.y) * sc.y + sh.y, 0.f);
        float c = fmaxf(bf2f(u.z) * sc.z + sh.z, 0.f);
        float d = fmaxf(bf2f(u.w) * sc.w + sh.w, 0.f);
        lsum += a + b + c + d;
        lsq  += a * a + b * b + c * c + d * d;
    }
    for (int o = 32; o > 0; o >>= 1) {
        lsum += __shfl_down(lsum, o);
        lsq  += __shfl_down(lsq, o);
    }
    __shared__ float w1[4], w2[4];
    int wid = threadIdx.x >> 6, lane = threadIdx.x & 63;
    if (lane == 0) { w1[wid] = lsum; w2[wid] = lsq; }
    __syncthreads();
    if (threadIdx.x == 0) {
        atomicAdd(lnacc,     (double)(w1[0] + w1[1] + w1[2] + w1[3]));
        atomicAdd(lnacc + 1, (double)(w2[0] + w2[1] + w2[2] + w2[3]));
    }
}

// ---------------- global stats (LN2 over z, fp32) ----------------
__global__ __launch_bounds__(256) void global_stats(const float* __restrict__ X, int total4, double* acc) {
    float s = 0.f, ss = 0.f;
    for (int t = blockIdx.x * 256 + threadIdx.x; t < total4; t += gridDim.x * 256) {
        float4 v = ((const float4*)X)[t];
        s  += v.x + v.y + v.z + v.w;
        ss += v.x * v.x + v.y * v.y + v.z * v.z + v.w * v.w;
    }
    for (int o = 32; o > 0; o >>= 1) {
        s += __shfl_down(s, o);
        ss += __shfl_down(ss, o);
    }
    __shared__ float w1[4], w2[4];
    int wid = threadIdx.x >> 6, lane = threadIdx.x & 63;
    if (lane == 0) { w1[wid] = s; w2[wid] = ss; }
    __syncthreads();
    if (threadIdx.x == 0) {
        atomicAdd(acc,     (double)(w1[0] + w1[1] + w1[2] + w1[3]));
        atomicAdd(acc + 1, (double)(w2[0] + w2[1] + w2[2] + w2[3]));
    }
}

// ---------------- LN finalize: per-channel affine a[c], c[c] ----------------
__global__ void ln_finalize(const double* __restrict__ acc, const float* __restrict__ w,
                            const float* __restrict__ b, float* __restrict__ a,
                            float* __restrict__ c, int cols, double invCount) {
    __shared__ float smu, sinv;
    if (threadIdx.x == 0) {
        double mu  = acc[0] * invCount;
        double var = acc[1] * invCount - mu * mu;
        if (var < 0.0) var = 0.0;
        float stdv = sqrtf((float)var);
        smu = (float)mu;
        sinv = 1.0f / (stdv + 1e-5f);
    }
    __syncthreads();
    int ci = threadIdx.x;
    if (ci < cols) {
        float A = sinv * w[ci];
        a[ci] = A;
        c[ci] = b[ci] - smu * A;
    }
}

// ---------------- fused BN+ReLU+LN + per-graph max pool -> bf16 ----------------
__global__ __launch_bounds__(256) void pool_ln_b(const unsigned short* __restrict__ H,
                                                 const float* __restrict__ sc_, const float* __restrict__ sh_,
                                                 const float* __restrict__ a, const float* __restrict__ c,
                                                 unsigned short* __restrict__ P) {
    int g = blockIdx.x;
    int c0 = threadIdx.x * 4;
    float4 sc = *(const float4*)(sc_ + c0);
    float4 sh = *(const float4*)(sh_ + c0);
    float4 av = *(const float4*)(a + c0);
    float4 cv = *(const float4*)(c + c0);
    float4 m = make_float4(-1e30f, -1e30f, -1e30f, -1e30f);
    const unsigned short* row = H + (size_t)g * 32 * HID2 + c0;
    for (int n = 0; n < 32; ++n, row += HID2) {
        ushort4 u = *(const ushort4*)row;
        m.x = fmaxf(m.x, fmaxf(bf2f(u.x) * sc.x + sh.x, 0.f) * av.x + cv.x);
        m.y = fmaxf(m.y, fmaxf(bf2f(u.y) * sc.y + sh.y, 0.f) * av.y + cv.y);
        m.z = fmaxf(m.z, fmaxf(bf2f(u.z) * sc.z + sh.z, 0.f) * av.z + cv.z);
        m.w = fmaxf(m.w, fmaxf(bf2f(u.w) * sc.w + sh.w, 0.f) * av.w + cv.w);
    }
    ushort4 o;
    o.x = f2bf(m.x); o.y = f2bf(m.y); o.z = f2bf(m.z); o.w = f2bf(m.w);
    *(ushort4*)(P + (size_t)g * HID2 + c0) = o;
}

// ---------------- fused LN2 + final GEMM [1024,512]@[512,20] + log_softmax ----------------
__global__ __launch_bounds__(64) void gemm4_lsm(const float* __restrict__ Z,
                                                const float* __restrict__ a,
                                                const float* __restrict__ c,
                                                const float* __restrict__ W,
                                                const float* __restrict__ bias,
                                                float* __restrict__ out) {
    __shared__ float zs[HID1];
    __shared__ float logits[NCLS];
    __shared__ float smax, slse;
    int m = blockIdx.x;
    for (int k = threadIdx.x; k < HID1; k += 64)
        zs[k] = Z[(size_t)m * HID1 + k] * a[k] + c[k];
    __syncthreads();
    if (threadIdx.x < NCLS) {
        float acc = bias[threadIdx.x];
        for (int k = 0; k < HID1; ++k)
            acc += zs[k] * W[k * NCLS + threadIdx.x];
        logits[threadIdx.x] = acc;
    }
    __syncthreads();
    if (threadIdx.x == 0) {
        float mx = -1e30f;
        for (int j = 0; j < NCLS; ++j) mx = fmaxf(mx, logits[j]);
        float s = 0.f;
        for (int j = 0; j < NCLS; ++j) s += expf(logits[j] - mx);
        smax = mx; slse = logf(s);
    }
    __syncthreads();
    if (threadIdx.x < NCLS)
        out[(size_t)m * NCLS + threadIdx.x] = logits[threadIdx.x] - smax - slse;
}

// ======================== launch ========================
extern "C" void kernel_launch(void* const* d_in, const int* in_sizes, int n_in,
                              void* d_out, int out_size, void* d_ws, size_t ws_size,
                              hipStream_t stream) {
    const float* x       = (const float*)d_in[0];
    const int*   ei      = (const int*)d_in[1];
    const int*   src     = ei;
    const int*   dst     = ei + NEDGES;
    const float* conv1_w = (const float*)d_in[3];
    const float* conv1_b = (const float*)d_in[4];
    const float* bn1_w   = (const float*)d_in[5];
    const float* bn1_b   = (const float*)d_in[6];
    const float* conv2_w = (const float*)d_in[7];
    const float* conv2_b = (const float*)d_in[8];
    const float* bn2_w   = (const float*)d_in[9];
    const float* bn2_b   = (const float*)d_in[10];
    const float* ln1_w   = (const float*)d_in[11];
    const float* ln1_b   = (const float*)d_in[12];
    const float* lin1_w  = (const float*)d_in[13];
    const float* lin1_b  = (const float*)d_in[14];
    const float* ln2_w   = (const float*)d_in[15];
    const float* ln2_b   = (const float*)d_in[16];
    const float* lin2_w  = (const float*)d_in[17];
    const float* lin2_b  = (const float*)d_in[18];
    float* out = (float*)d_out;

    // ---- workspace layout (peak 120 MB) ----
    char* ws = (char*)d_ws;
    const size_t KB = 1024, MB = 1048576;
    float*          dis     = (float*)(ws + 0);            // 128K
    float*          sF      = (float*)(ws + 128 * KB);     // 64K stats
    unsigned short* w1t     = (unsigned short*)(ws + 256 * KB);   // [512][128]  128K
    unsigned short* w2t     = (unsigned short*)(ws + 512 * KB);   // [1024][512] 1M
    unsigned short* w3t     = (unsigned short*)(ws + 1536 * KB);  // [512][1024] 1M
    int*            cnt     = (int*)(ws + 2560 * KB);      // 128K
    int*            offs    = (int*)(ws + 2688 * KB);      // 128K+4 (192K reserved)
    int*            cursor  = (int*)(ws + 2880 * KB);      // 128K
    int*            csr_src = (int*)(ws + 3 * MB);         // 1M
    float*          csr_w   = (float*)(ws + 4 * MB);       // 1M
    unsigned short* pool    = (unsigned short*)(ws + 5 * MB);   // [1024][1024] bf16 2M
    float*          z       = (float*)(ws + 7 * MB);       // [1024][512] f32 2M
    unsigned short* agg1    = (unsigned short*)(ws + 16 * MB);  // [N,128] bf16 8M   (16-24)
    unsigned short* h1      = (unsigned short*)(ws + 24 * MB);  // [N,512] bf16 32M  (24-56)
    unsigned short* h2      = (unsigned short*)(ws + 16 * MB);  // [N,1024] bf16 64M (16-80, overlays dead agg1+h1)
    unsigned short* agg2    = (unsigned short*)(ws + 88 * MB);  // [N,512] bf16 32M  (88-120)

    float* bn1_sum = sF + 0,      *bn1_sq    = sF + 512;
    float* bn1_scale = sF + 1024, *bn1_shift = sF + 1536;
    float* bn2_sum = sF + 2048,   *bn2_sq    = sF + 3072;
    float* bn2_scale = sF + 4096, *bn2_shift = sF + 5120;
    float* ln1_a = sF + 6144, *ln1_c = sF + 7168;
    float* ln2_a = sF + 8192, *ln2_c = sF + 8704;
    double* lnacc = (double*)(sF + 9216);   // [0,1]=ln1  [2,3]=ln2

    hipMemsetAsync(sF, 0, 40960, stream);
    hipMemsetAsync(cnt, 0, NNODES * 4, stream);

    // ---- weight transposes (bf16) ----
    wtrans<<<dim3(HID1 / 64, FIN / 64),  256, 0, stream>>>(conv1_w, w1t, FIN, HID1);
    wtrans<<<dim3(HID2 / 64, HID1 / 64), 256, 0, stream>>>(conv2_w, w2t, HID1, HID2);
    wtrans<<<dim3(HID1 / 64, HID2 / 64), 256, 0, stream>>>(lin1_w,  w3t, HID2, HID1);

    // ---- CSR build (by dst) + dis ----
    csr_count<<<(NEDGES + 255) / 256, 256, 0, stream>>>(dst, cnt);
    csr_scan<<<1, 1024, 0, stream>>>(cnt, offs, cursor, dis);
    csr_fill<<<(NEDGES + 255) / 256, 256, 0, stream>>>(src, dst, dis, cursor, csr_src, csr_w);

    // ---- conv1: agg1 = A @ x ; h1 = agg1 @ W1 + b1 (+ fused bn1 col stats) ----
    gcn_gather<FIN, 0><<<NNODES / 4, 256, 0, stream>>>(x, offs, csr_src, csr_w, dis, agg1);
    gemm_mfma<0, 1, 1><<<dim3(HID1 / 128, NNODES / 128), 256, 0, stream>>>(agg1, w1t, conv1_b, h1, bn1_sum, bn1_sq, NNODES, HID1, FIN);

    // ---- bn1 + relu (in place) ----
    bn_finalize<<<(HID1 + 255) / 256, 256, 0, stream>>>(bn1_sum, bn1_sq, bn1_w, bn1_b, bn1_scale, bn1_shift, HID1, 1.0f / NNODES);
    bn_apply_b<<<2048, 256, 0, stream>>>(h1, bn1_scale, bn1_shift, NNODES * HID1 / 4, HID1 / 4 - 1);

    // ---- conv2: agg2 = A @ h1 ; h2 = agg2 @ W2 + b2 (+ fused bn2 col stats; h2 stays RAW) ----
    gcn_gather<HID1, 1><<<NNODES / 4, 256, 0, stream>>>(h1, offs, csr_src, csr_w, dis, agg2);
    gemm_mfma<0, 1, 1><<<dim3(HID2 / 128, NNODES / 128), 256, 0, stream>>>(agg2, w2t, conv2_b, h2, bn2_sum, bn2_sq, NNODES, HID2, HID1);

    // ---- bn2 coeffs; LN1 stats over relu(bn(h2)) (read-only) ----
    bn_finalize<<<(HID2 + 255) / 256, 256, 0, stream>>>(bn2_sum, bn2_sq, bn2_w, bn2_b, bn2_scale, bn2_shift, HID2, 1.0f / NNODES);
    bn_lnstats<<<2048, 256, 0, stream>>>(h2, bn2_scale, bn2_shift, NNODES * HID2 / 4, HID2 / 4 - 1, lnacc);

    // ---- LN1 affine + fused BN+ReLU+LN+pool (bf16 out) ----
    ln_finalize<<<1, HID2, 0, stream>>>(lnacc, ln1_w, ln1_b, ln1_a, ln1_c, HID2, 1.0 / ((double)NNODES * HID2));
    pool_ln_b<<<NGRAPH, 256, 0, stream>>>(h2, bn2_scale, bn2_shift, ln1_a, ln1_c, pool);

    // ---- lin1 + relu (MFMA, f32 out) ----
    gemm_mfma<1, 0, 0><<<dim3(HID1 / 128, NGRAPH / 128), 256, 0, stream>>>(pool, w3t, lin1_b, z, nullptr, nullptr, NGRAPH, HID1, HID2);

    // ---- LN2 + lin2 + log_softmax ----
    global_stats<<<512, 256, 0, stream>>>(z, NGRAPH * HID1 / 4, lnacc + 2);
    ln_finalize<<<1, HID1, 0, stream>>>(lnacc + 2, ln2_w, ln2_b, ln2_a, ln2_c, HID1, 1.0 / ((double)NGRAPH * HID1));
    gemm4_lsm<<<NGRAPH, 64, 0, stream>>>(z, ln2_a, ln2_c, lin2_w, lin2_b, out);
}

// Round 6
// 352.160 us; speedup vs baseline: 8.4984x; 1.4431x over previous
//
#include <hip/hip_runtime.h>
#include <hip/hip_bf16.h>

#define NNODES 32768
#define NEDGES 262144
#define FIN    128
#define HID1   512
#define HID2   1024
#define NGRAPH 1024
#define NCLS   20

typedef __attribute__((ext_vector_type(8))) short bf16x8;
typedef __attribute__((ext_vector_type(4))) float f32x4;

// ---- bf16 bit helpers (RNE) ----
__device__ inline float bf2f(unsigned short u) {
    union { unsigned int i; float f; } v; v.i = ((unsigned int)u) << 16; return v.f;
}
__device__ inline unsigned short f2bf(float f) {
    union { unsigned int i; float f; } v; v.f = f;
    unsigned int r = v.i + 0x7FFF + ((v.i >> 16) & 1);
    return (unsigned short)(r >> 16);
}

// ---- async global -> LDS, 16B per lane (dest = wave-uniform base + lane*16) ----
typedef unsigned int u32g __attribute__((address_space(1)));
typedef unsigned int u32l __attribute__((address_space(3)));
__device__ inline void load16_lds(const void* g, void* l) {
    __builtin_amdgcn_global_load_lds((const u32g*)g, (u32l*)l, 16, 0, 0);
}

// ================= weight transpose + bf16 convert: Wt[n][k] = bf16(W[k][n]) =================
__global__ __launch_bounds__(256) void wtrans(const float* __restrict__ W,
                                              unsigned short* __restrict__ Wt,
                                              int K, int N) {
    __shared__ unsigned short tile[64][72];
    int kb = blockIdx.y * 64, nb = blockIdx.x * 64;
    {
        int k = threadIdx.x >> 2;
        int n0 = (threadIdx.x & 3) * 16;
#pragma unroll
        for (int q = 0; q < 4; ++q) {
            float4 v = *(const float4*)(W + (size_t)(kb + k) * N + nb + n0 + q * 4);
            tile[k][n0 + q * 4 + 0] = f2bf(v.x);
            tile[k][n0 + q * 4 + 1] = f2bf(v.y);
            tile[k][n0 + q * 4 + 2] = f2bf(v.z);
            tile[k][n0 + q * 4 + 3] = f2bf(v.w);
        }
    }
    __syncthreads();
    {
        int n = threadIdx.x >> 2;
        int k0 = (threadIdx.x & 3) * 16;
#pragma unroll
        for (int q = 0; q < 4; ++q) {
            ushort4 u;
            u.x = tile[k0 + q * 4 + 0][n];
            u.y = tile[k0 + q * 4 + 1][n];
            u.z = tile[k0 + q * 4 + 2][n];
            u.w = tile[k0 + q * 4 + 3][n];
            *(ushort4*)(Wt + (size_t)(nb + n) * K + kb + k0 + q * 4) = u;
        }
    }
}

// ================= CSR build (by dst) =================
__global__ __launch_bounds__(256) void csr_count(const int* __restrict__ dst, int* __restrict__ cnt) {
    int e = blockIdx.x * 256 + threadIdx.x;
    if (e < NEDGES) atomicAdd(&cnt[dst[e]], 1);
}

__global__ __launch_bounds__(1024) void csr_scan(const int* __restrict__ cnt,
                                                 int* __restrict__ offs,
                                                 int* __restrict__ cursor,
                                                 float* __restrict__ dis) {
    __shared__ int part[1024];
    int t = threadIdx.x;
    int base = t * 32;
    int s = 0;
#pragma unroll
    for (int i = 0; i < 32; ++i) s += cnt[base + i];
    part[t] = s;
    __syncthreads();
    for (int off = 1; off < 1024; off <<= 1) {
        int v = (t >= off) ? part[t - off] : 0;
        __syncthreads();
        part[t] += v;
        __syncthreads();
    }
    int run = (t == 0) ? 0 : part[t - 1];
#pragma unroll
    for (int i = 0; i < 32; ++i) {
        int c = cnt[base + i];
        offs[base + i] = run;
        cursor[base + i] = run;
        dis[base + i] = rsqrtf((float)(c + 1));
        run += c;
    }
    if (t == 1023) offs[NNODES] = run;
}

__global__ __launch_bounds__(256) void csr_fill(const int* __restrict__ src,
                                                const int* __restrict__ dst,
                                                const float* __restrict__ dis,
                                                int* __restrict__ cursor,
                                                int* __restrict__ csr_src,
                                                float* __restrict__ csr_w) {
    int e = blockIdx.x * 256 + threadIdx.x;
    if (e >= NEDGES) return;
    int s = src[e], d = dst[e];
    int pos = atomicAdd(&cursor[d], 1);
    csr_src[pos] = s;
    csr_w[pos] = dis[s] * dis[d];
}

// ================= gather aggregation -> bf16 out =================
// BN=1: apply per-channel scale/shift + relu to every gathered row (fused BN+ReLU).
template<int F, int BFIN, int BN>
__global__ __launch_bounds__(256) void gcn_gather(const void* __restrict__ Xv,
                                                  const int* __restrict__ offs,
                                                  const int* __restrict__ csr_src,
                                                  const float* __restrict__ csr_w,
                                                  const float* __restrict__ dis,
                                                  const float* __restrict__ scale,
                                                  const float* __restrict__ shift,
                                                  unsigned short* __restrict__ out) {
    constexpr int CPL = F / 64;          // 2 (F=128) or 8 (F=512)
    int wave = threadIdx.x >> 6, lane = threadIdx.x & 63;
    int node = blockIdx.x * 4 + wave;
    int c0 = lane * CPL;
    float acc[CPL];
#pragma unroll
    for (int q = 0; q < CPL; ++q) acc[q] = 0.f;
    float sc[CPL], sh[CPL];
    if (BN) {
#pragma unroll
        for (int q = 0; q < CPL; ++q) { sc[q] = scale[c0 + q]; sh[q] = shift[c0 + q]; }
    }
    float sw = dis[node]; sw *= sw;

    int e0 = offs[node], e1 = offs[node + 1];
    // self term (e = -1) then edges
    for (int e = e0 - 1; e < e1; ++e) {
        int s; float w;
        if (e < e0) { s = node; w = sw; }
        else        { s = csr_src[e]; w = csr_w[e]; }
        if (BFIN) {
            const unsigned short* r = (const unsigned short*)Xv + (size_t)s * F + c0;
#pragma unroll
            for (int q = 0; q < (CPL + 3) / 4; ++q) {
                ushort4 u = *(const ushort4*)(r + q * 4);
                float v0 = bf2f(u.x), v1 = bf2f(u.y), v2 = bf2f(u.z), v3 = bf2f(u.w);
                if (BN) {
                    v0 = fmaxf(v0 * sc[q * 4 + 0] + sh[q * 4 + 0], 0.f);
                    v1 = fmaxf(v1 * sc[q * 4 + 1] + sh[q * 4 + 1], 0.f);
                    v2 = fmaxf(v2 * sc[q * 4 + 2] + sh[q * 4 + 2], 0.f);
                    v3 = fmaxf(v3 * sc[q * 4 + 3] + sh[q * 4 + 3], 0.f);
                }
                acc[q * 4 + 0] += w * v0; acc[q * 4 + 1] += w * v1;
                acc[q * 4 + 2] += w * v2; acc[q * 4 + 3] += w * v3;
            }
        } else if (CPL == 2) {
            float2 u = *(const float2*)((const float*)Xv + (size_t)s * F + c0);
            acc[0] += w * u.x; acc[1] += w * u.y;
        } else {
#pragma unroll
            for (int q = 0; q < (CPL + 3) / 4; ++q) {
                float4 u = *(const float4*)((const float*)Xv + (size_t)s * F + c0 + q * 4);
                acc[q * 4 + 0] += w * u.x; acc[q * 4 + 1] += w * u.y;
                acc[q * 4 + 2] += w * u.z; acc[q * 4 + 3] += w * u.w;
            }
        }
    }

    unsigned short* o = out + (size_t)node * F + c0;
    if (CPL == 2) {
        ushort2 u; u.x = f2bf(acc[0]); u.y = f2bf(acc[1]);
        *(ushort2*)o = u;
    } else {
#pragma unroll
        for (int q = 0; q < (CPL + 3) / 4; ++q) {
            ushort4 u;
            u.x = f2bf(acc[q * 4 + 0]); u.y = f2bf(acc[q * 4 + 1]);
            u.z = f2bf(acc[q * 4 + 2]); u.w = f2bf(acc[q * 4 + 3]);
            *(ushort4*)(o + q * 4) = u;
        }
    }
}

// ================= bf16 MFMA GEMM: C[M][N] = A[M][K] @ B (Bt[N][K]) =================
// 128x128 tile, BK=64, 4 waves. global_load_lds staging (no VGPR roundtrip, no spills).
// LDS XOR-swizzle via pre-swizzled global source (linear dest) + swizzled ds_read.
// CBF16=1: LDS-staged coalesced bf16 store. STATS=1: fused per-column sum/sumsq atomics.
template<int EPI, int CBF16, int STATS>
__global__ __launch_bounds__(256, 2) void gemm_mfma(const unsigned short* __restrict__ A,
                                                    const unsigned short* __restrict__ Bt,
                                                    const float* __restrict__ bias,
                                                    void* __restrict__ Cv,
                                                    float* __restrict__ gsum,
                                                    float* __restrict__ gsq,
                                                    int M, int N, int K) {
    constexpr int BM = 128, BN = 128, BK = 64;
    __shared__ unsigned short smem[128 * 136];   // K-loop: As[0..8191], Bs[8192..16383]; epilogue: C tile 128x136
    unsigned short* As = smem;
    unsigned short* Bs = smem + BM * BK;

    const int tid = threadIdx.x;
    const int lane = tid & 63;
    const int wave = tid >> 6;
    const int wr = wave >> 1, wc = wave & 1;

    // XCD-bijective swizzle (nwg % 8 == 0 for all our grids)
    const int nwg = gridDim.x * gridDim.y;
    const int wg = blockIdx.y * gridDim.x + blockIdx.x;
    const int cpx = nwg >> 3;
    const int swz = (wg & 7) * cpx + (wg >> 3);
    const int m0 = (swz / gridDim.x) * BM, n0 = (swz % gridDim.x) * BN;

    // staging source map: linear LDS byte Ld = i*4096 + tid*16 -> row r = i*32 + (tid>>3),
    // row-byte subL = (tid&7)*16; content there must be global byte subL ^ ((r&7)<<4).
    // (r&7) == ((tid>>3)&7) for all rounds i since i*32 % 8 == 0 -> per-thread constant.
    const int sub = ((tid & 7) * 16) ^ (((tid >> 3) & 7) << 4);
    const int rbase = tid >> 3;
    const char* Ab = (const char*)A + sub;
    const char* Bb = (const char*)Bt + sub;

    f32x4 acc[4][4] = {};

    for (int k0 = 0; k0 < K; k0 += BK) {
        __syncthreads();   // previous iteration's LDS reads complete before overwrite
#pragma unroll
        for (int i = 0; i < 4; ++i) {
            int r = i * 32 + rbase;
            load16_lds(Ab + ((size_t)(m0 + r) * K + k0) * 2, (char*)As + i * 4096 + tid * 16);
            load16_lds(Bb + ((size_t)(n0 + r) * K + k0) * 2, (char*)Bs + i * 4096 + tid * 16);
        }
        __syncthreads();   // compiler drains vmcnt before barrier -> LDS tile ready
#pragma unroll
        for (int ks = 0; ks < 2; ++ks) {
            bf16x8 af[4], bfr[4];
#pragma unroll
            for (int m = 0; m < 4; ++m) {
                int row = wr * 64 + m * 16 + (lane & 15);
                int s = (ks * 64 + ((lane >> 4) * 16)) ^ ((row & 7) << 4);
                af[m] = *(const bf16x8*)((const char*)As + row * 128 + s);
            }
#pragma unroll
            for (int n = 0; n < 4; ++n) {
                int row = wc * 64 + n * 16 + (lane & 15);
                int s = (ks * 64 + ((lane >> 4) * 16)) ^ ((row & 7) << 4);
                bfr[n] = *(const bf16x8*)((const char*)Bs + row * 128 + s);
            }
#pragma unroll
            for (int m = 0; m < 4; ++m)
#pragma unroll
                for (int n = 0; n < 4; ++n)
                    acc[m][n] = __builtin_amdgcn_mfma_f32_16x16x32_bf16(af[m], bfr[n], acc[m][n], 0, 0, 0);
        }
    }

    // ---- epilogue ----
    // C fragment mapping: row = wr*64 + m*16 + (lane>>4)*4 + j ; col = wc*64 + n*16 + (lane&15)
    if (CBF16) {
        __syncthreads();                         // MFMA LDS reads done; reuse smem for C tile
        float cs[4], cq[4];
#pragma unroll
        for (int n = 0; n < 4; ++n) { cs[n] = 0.f; cq[n] = 0.f; }
#pragma unroll
        for (int n = 0; n < 4; ++n) {
            int col = wc * 64 + n * 16 + (lane & 15);
            float bsv = bias[n0 + col];
#pragma unroll
            for (int m = 0; m < 4; ++m) {
                int rbase2 = wr * 64 + m * 16 + ((lane >> 4) << 2);
#pragma unroll
                for (int j = 0; j < 4; ++j) {
                    float v = acc[m][n][j] + bsv;
                    if (STATS) { cs[n] += v; cq[n] += v * v; }
                    if (EPI == 1) v = fmaxf(v, 0.f);
                    smem[(rbase2 + j) * 136 + col] = f2bf(v);
                }
            }
        }
        if (STATS) {
#pragma unroll
            for (int n = 0; n < 4; ++n) {
                cs[n] += __shfl_xor(cs[n], 16); cs[n] += __shfl_xor(cs[n], 32);
                cq[n] += __shfl_xor(cq[n], 16); cq[n] += __shfl_xor(cq[n], 32);
            }
            if (lane < 16) {
#pragma unroll
                for (int n = 0; n < 4; ++n) {
                    int col = n0 + wc * 64 + n * 16 + lane;
                    atomicAdd(&gsum[col], cs[n]);
                    atomicAdd(&gsq[col],  cq[n]);
                }
            }
        }
        __syncthreads();
        // coalesced store: 16 rows x 16 chunks of 16B per iteration
#pragma unroll
        for (int it = 0; it < 8; ++it) {
            int r = it * 16 + (tid >> 4);
            int ch = tid & 15;
            int4 v = *(const int4*)&smem[r * 136 + ch * 8];
            *(int4*)((unsigned short*)Cv + (size_t)(m0 + r) * N + n0 + ch * 8) = v;
        }
    } else {
#pragma unroll
        for (int m = 0; m < 4; ++m) {
            int row = m0 + wr * 64 + m * 16 + ((lane >> 4) << 2);
#pragma unroll
            for (int n = 0; n < 4; ++n) {
                int col = n0 + wc * 64 + n * 16 + (lane & 15);
                float bsv = bias[col];
#pragma unroll
                for (int j = 0; j < 4; ++j) {
                    float v = acc[m][n][j] + bsv;
                    if (EPI == 1) v = fmaxf(v, 0.f);
                    ((float*)Cv)[(size_t)(row + j) * N + col] = v;
                }
            }
        }
    }
}

__global__ void bn_finalize(const float* __restrict__ sum, const float* __restrict__ sq,
                            const float* __restrict__ w, const float* __restrict__ b,
                            float* __restrict__ scale, float* __restrict__ shift,
                            int cols, float invN) {
    int c = blockIdx.x * blockDim.x + threadIdx.x;
    if (c >= cols) return;
    float mu = sum[c] * invN;
    float var = sq[c] * invN - mu * mu;
    float sc = rsqrtf(var + 1e-5f) * w[c];
    scale[c] = sc;
    shift[c] = b[c] - mu * sc;
}

// ---------------- read-only: LN stats of relu(bn(h2)) ----------------
__global__ __launch_bounds__(256) void bn_lnstats(const unsigned short* __restrict__ X,
                                                  const float* __restrict__ scale,
                                                  const float* __restrict__ shift,
                                                  int total4, int c4mask, double* lnacc) {
    float lsum = 0.f, lsq = 0.f;
    for (int t = blockIdx.x * 256 + threadIdx.x; t < total4; t += gridDim.x * 256) {
        int c4 = (t & c4mask) * 4;
        ushort4 u = ((const ushort4*)X)[t];
        float4 sc = *(const float4*)(scale + c4);
        float4 sh = *(const float4*)(shift + c4);
        float a = fmaxf(bf2f(u.x) * sc.x + sh.x, 0.f);
        float b = fmaxf(bf2f(u.y) * sc.y + sh.y, 0.f);
        float c = fmaxf(bf2f(u.z) * sc.z + sh.z, 0.f);
        float d = fmaxf(bf2f(u.w) * sc.w + sh.w, 0.f);
        lsum += a + b + c + d;
        lsq  += a * a + b * b + c * c + d * d;
    }
    for (int o = 32; o > 0; o >>= 1) {
        lsum += __shfl_down(lsum, o);
        lsq  += __shfl_down(lsq, o);
    }
    __shared__ float w1[4], w2[4];
    int wid = threadIdx.x >> 6, lane = threadIdx.x & 63;
    if (lane == 0) { w1[wid] = lsum; w2[wid] = lsq; }
    __syncthreads();
    if (threadIdx.x == 0) {
        atomicAdd(lnacc,     (double)(w1[0] + w1[1] + w1[2] + w1[3]));
        atomicAdd(lnacc + 1, (double)(w2[0] + w2[1] + w2[2] + w2[3]));
    }
}

// ---------------- global stats (LN2 over z, fp32) ----------------
__global__ __launch_bounds__(256) void global_stats(const float* __restrict__ X, int total4, double* acc) {
    float s = 0.f, ss = 0.f;
    for (int t = blockIdx.x * 256 + threadIdx.x; t < total4; t += gridDim.x * 256) {
        float4 v = ((const float4*)X)[t];
        s  += v.x + v.y + v.z + v.w;
        ss += v.x * v.x + v.y * v.y + v.z * v.z + v.w * v.w;
    }
    for (int o = 32; o > 0; o >>= 1) {
        s += __shfl_down(s, o);
        ss += __shfl_down(ss, o);
    }
    __shared__ float w1[4], w2[4];
    int wid = threadIdx.x >> 6, lane = threadIdx.x & 63;
    if (lane == 0) { w1[wid] = s; w2[wid] = ss; }
    __syncthreads();
    if (threadIdx.x == 0) {
        atomicAdd(acc,     (double)(w1[0] + w1[1] + w1[2] + w1[3]));
        atomicAdd(acc + 1, (double)(w2[0] + w2[1] + w2[2] + w2[3]));
    }
}

// ---------------- LN finalize: per-channel affine a[c], c[c] ----------------
__global__ void ln_finalize(const double* __restrict__ acc, const float* __restrict__ w,
                            const float* __restrict__ b, float* __restrict__ a,
                            float* __restrict__ c, int cols, double invCount) {
    __shared__ float smu, sinv;
    if (threadIdx.x == 0) {
        double mu  = acc[0] * invCount;
        double var = acc[1] * invCount - mu * mu;
        if (var < 0.0) var = 0.0;
        float stdv = sqrtf((float)var);
        smu = (float)mu;
        sinv = 1.0f / (stdv + 1e-5f);
    }
    __syncthreads();
    int ci = threadIdx.x;
    if (ci < cols) {
        float A = sinv * w[ci];
        a[ci] = A;
        c[ci] = b[ci] - smu * A;
    }
}

// ---------------- fused BN+ReLU+LN + per-graph max pool -> bf16 ----------------
__global__ __launch_bounds__(256) void pool_ln_b(const unsigned short* __restrict__ H,
                                                 const float* __restrict__ sc_, const float* __restrict__ sh_,
                                                 const float* __restrict__ a, const float* __restrict__ c,
                                                 unsigned short* __restrict__ P) {
    int g = blockIdx.x;
    int c0 = threadIdx.x * 4;
    float4 sc = *(const float4*)(sc_ + c0);
    float4 sh = *(const float4*)(sh_ + c0);
    float4 av = *(const float4*)(a + c0);
    float4 cv = *(const float4*)(c + c0);
    float4 m = make_float4(-1e30f, -1e30f, -1e30f, -1e30f);
    const unsigned short* row = H + (size_t)g * 32 * HID2 + c0;
    for (int n = 0; n < 32; ++n, row += HID2) {
        ushort4 u = *(const ushort4*)row;
        m.x = fmaxf(m.x, fmaxf(bf2f(u.x) * sc.x + sh.x, 0.f) * av.x + cv.x);
        m.y = fmaxf(m.y, fmaxf(bf2f(u.y) * sc.y + sh.y, 0.f) * av.y + cv.y);
        m.z = fmaxf(m.z, fmaxf(bf2f(u.z) * sc.z + sh.z, 0.f) * av.z + cv.z);
        m.w = fmaxf(m.w, fmaxf(bf2f(u.w) * sc.w + sh.w, 0.f) * av.w + cv.w);
    }
    ushort4 o;
    o.x = f2bf(m.x); o.y = f2bf(m.y); o.z = f2bf(m.z); o.w = f2bf(m.w);
    *(ushort4*)(P + (size_t)g * HID2 + c0) = o;
}

// ---------------- fused LN2 + final GEMM [1024,512]@[512,20] + log_softmax ----------------
__global__ __launch_bounds__(64) void gemm4_lsm(const float* __restrict__ Z,
                                                const float* __restrict__ a,
                                                const float* __restrict__ c,
                                                const float* __restrict__ W,
                                                const float* __restrict__ bias,
                                                float* __restrict__ out) {
    __shared__ float zs[HID1];
    __shared__ float logits[NCLS];
    __shared__ float smax, slse;
    int m = blockIdx.x;
    for (int k = threadIdx.x; k < HID1; k += 64)
        zs[k] = Z[(size_t)m * HID1 + k] * a[k] + c[k];
    __syncthreads();
    if (threadIdx.x < NCLS) {
        float acc = bias[threadIdx.x];
        for (int k = 0; k < HID1; ++k)
            acc += zs[k] * W[k * NCLS + threadIdx.x];
        logits[threadIdx.x] = acc;
    }
    __syncthreads();
    if (threadIdx.x == 0) {
        float mx = -1e30f;
        for (int j = 0; j < NCLS; ++j) mx = fmaxf(mx, logits[j]);
        float s = 0.f;
        for (int j = 0; j < NCLS; ++j) s += expf(logits[j] - mx);
        smax = mx; slse = logf(s);
    }
    __syncthreads();
    if (threadIdx.x < NCLS)
        out[(size_t)m * NCLS + threadIdx.x] = logits[threadIdx.x] - smax - slse;
}

// ======================== launch ========================
extern "C" void kernel_launch(void* const* d_in, const int* in_sizes, int n_in,
                              void* d_out, int out_size, void* d_ws, size_t ws_size,
                              hipStream_t stream) {
    const float* x       = (const float*)d_in[0];
    const int*   ei      = (const int*)d_in[1];
    const int*   src     = ei;
    const int*   dst     = ei + NEDGES;
    const float* conv1_w = (const float*)d_in[3];
    const float* conv1_b = (const float*)d_in[4];
    const float* bn1_w   = (const float*)d_in[5];
    const float* bn1_b   = (const float*)d_in[6];
    const float* conv2_w = (const float*)d_in[7];
    const float* conv2_b = (const float*)d_in[8];
    const float* bn2_w   = (const float*)d_in[9];
    const float* bn2_b   = (const float*)d_in[10];
    const float* ln1_w   = (const float*)d_in[11];
    const float* ln1_b   = (const float*)d_in[12];
    const float* lin1_w  = (const float*)d_in[13];
    const float* lin1_b  = (const float*)d_in[14];
    const float* ln2_w   = (const float*)d_in[15];
    const float* ln2_b   = (const float*)d_in[16];
    const float* lin2_w  = (const float*)d_in[17];
    const float* lin2_b  = (const float*)d_in[18];
    float* out = (float*)d_out;

    // ---- workspace layout (peak 120 MB) ----
    char* ws = (char*)d_ws;
    const size_t KB = 1024, MB = 1048576;
    float*          dis     = (float*)(ws + 0);            // 128K
    float*          sF      = (float*)(ws + 128 * KB);     // 64K stats
    unsigned short* w1t     = (unsigned short*)(ws + 256 * KB);   // [512][128]  128K
    unsigned short* w2t     = (unsigned short*)(ws + 512 * KB);   // [1024][512] 1M
    unsigned short* w3t     = (unsigned short*)(ws + 1536 * KB);  // [512][1024] 1M
    int*            cnt     = (int*)(ws + 2560 * KB);      // 128K
    int*            offs    = (int*)(ws + 2688 * KB);      // 128K+4 (192K reserved)
    int*            cursor  = (int*)(ws + 2880 * KB);      // 128K
    int*            csr_src = (int*)(ws + 3 * MB);         // 1M
    float*          csr_w   = (float*)(ws + 4 * MB);       // 1M
    unsigned short* pool    = (unsigned short*)(ws + 5 * MB);   // [1024][1024] bf16 2M
    float*          z       = (float*)(ws + 7 * MB);       // [1024][512] f32 2M
    unsigned short* agg1    = (unsigned short*)(ws + 16 * MB);  // [N,128] bf16 8M   (16-24)
    unsigned short* h1      = (unsigned short*)(ws + 24 * MB);  // [N,512] bf16 32M  (24-56)
    unsigned short* h2      = (unsigned short*)(ws + 16 * MB);  // [N,1024] bf16 64M (16-80, overlays dead agg1+h1)
    unsigned short* agg2    = (unsigned short*)(ws + 88 * MB);  // [N,512] bf16 32M  (88-120)

    float* bn1_sum = sF + 0,      *bn1_sq    = sF + 512;
    float* bn1_scale = sF + 1024, *bn1_shift = sF + 1536;
    float* bn2_sum = sF + 2048,   *bn2_sq    = sF + 3072;
    float* bn2_scale = sF + 4096, *bn2_shift = sF + 5120;
    float* ln1_a = sF + 6144, *ln1_c = sF + 7168;
    float* ln2_a = sF + 8192, *ln2_c = sF + 8704;
    double* lnacc = (double*)(sF + 9216);   // [0,1]=ln1  [2,3]=ln2

    hipMemsetAsync(sF, 0, 40960, stream);
    hipMemsetAsync(cnt, 0, NNODES * 4, stream);

    // ---- weight transposes (bf16) ----
    wtrans<<<dim3(HID1 / 64, FIN / 64),  256, 0, stream>>>(conv1_w, w1t, FIN, HID1);
    wtrans<<<dim3(HID2 / 64, HID1 / 64), 256, 0, stream>>>(conv2_w, w2t, HID1, HID2);
    wtrans<<<dim3(HID1 / 64, HID2 / 64), 256, 0, stream>>>(lin1_w,  w3t, HID2, HID1);

    // ---- CSR build (by dst) + dis ----
    csr_count<<<(NEDGES + 255) / 256, 256, 0, stream>>>(dst, cnt);
    csr_scan<<<1, 1024, 0, stream>>>(cnt, offs, cursor, dis);
    csr_fill<<<(NEDGES + 255) / 256, 256, 0, stream>>>(src, dst, dis, cursor, csr_src, csr_w);

    // ---- conv1: agg1 = A @ x ; h1 = agg1 @ W1 + b1 (+ fused bn1 col stats; h1 stays RAW) ----
    gcn_gather<FIN, 0, 0><<<NNODES / 4, 256, 0, stream>>>(x, offs, csr_src, csr_w, dis, nullptr, nullptr, agg1);
    gemm_mfma<0, 1, 1><<<dim3(HID1 / 128, NNODES / 128), 256, 0, stream>>>(agg1, w1t, conv1_b, h1, bn1_sum, bn1_sq, NNODES, HID1, FIN);

    // ---- bn1 coeffs; conv2 gather applies BN1+ReLU on the fly ----
    bn_finalize<<<(HID1 + 255) / 256, 256, 0, stream>>>(bn1_sum, bn1_sq, bn1_w, bn1_b, bn1_scale, bn1_shift, HID1, 1.0f / NNODES);
    gcn_gather<HID1, 1, 1><<<NNODES / 4, 256, 0, stream>>>(h1, offs, csr_src, csr_w, dis, bn1_scale, bn1_shift, agg2);
    gemm_mfma<0, 1, 1><<<dim3(HID2 / 128, NNODES / 128), 256, 0, stream>>>(agg2, w2t, conv2_b, h2, bn2_sum, bn2_sq, NNODES, HID2, HID1);

    // ---- bn2 coeffs; LN1 stats over relu(bn(h2)) (read-only) ----
    bn_finalize<<<(HID2 + 255) / 256, 256, 0, stream>>>(bn2_sum, bn2_sq, bn2_w, bn2_b, bn2_scale, bn2_shift, HID2, 1.0f / NNODES);
    bn_lnstats<<<2048, 256, 0, stream>>>(h2, bn2_scale, bn2_shift, NNODES * HID2 / 4, HID2 / 4 - 1, lnacc);

    // ---- LN1 affine + fused BN+ReLU+LN+pool (bf16 out) ----
    ln_finalize<<<1, HID2, 0, stream>>>(lnacc, ln1_w, ln1_b, ln1_a, ln1_c, HID2, 1.0 / ((double)NNODES * HID2));
    pool_ln_b<<<NGRAPH, 256, 0, stream>>>(h2, bn2_scale, bn2_shift, ln1_a, ln1_c, pool);

    // ---- lin1 + relu (MFMA, f32 out) ----
    gemm_mfma<1, 0, 0><<<dim3(HID1 / 128, NGRAPH / 128), 256, 0, stream>>>(pool, w3t, lin1_b, z, nullptr, nullptr, NGRAPH, HID1, HID2);

    // ---- LN2 + lin2 + log_softmax ----
    global_stats<<<512, 256, 0, stream>>>(z, NGRAPH * HID1 / 4, lnacc + 2);
    ln_finalize<<<1, HID1, 0, stream>>>(lnacc + 2, ln2_w, ln2_b, ln2_a, ln2_c, HID1, 1.0 / ((double)NGRAPH * HID1));
    gemm4_lsm<<<NGRAPH, 64, 0, stream>>>(z, ln2_a, ln2_c, lin2_w, lin2_b, out);
}

// Round 7
// 320.060 us; speedup vs baseline: 9.3507x; 1.1003x over previous
//
#include <hip/hip_runtime.h>
#include <hip/hip_bf16.h>

#define NNODES 32768
#define NEDGES 262144
#define FIN    128
#define HID1   512
#define HID2   1024
#define NGRAPH 1024
#define NCLS   20

typedef __attribute__((ext_vector_type(8))) short bf16x8;
typedef __attribute__((ext_vector_type(4))) float f32x4;

// ---- bf16 bit helpers (RNE) ----
__device__ inline float bf2f(unsigned short u) {
    union { unsigned int i; float f; } v; v.i = ((unsigned int)u) << 16; return v.f;
}
__device__ inline unsigned short f2bf(float f) {
    union { unsigned int i; float f; } v; v.f = f;
    unsigned int r = v.i + 0x7FFF + ((v.i >> 16) & 1);
    return (unsigned short)(r >> 16);
}

// ---- async global -> LDS, 16B per lane (dest = wave-uniform base + lane*16) ----
typedef unsigned int u32g __attribute__((address_space(1)));
typedef unsigned int u32l __attribute__((address_space(3)));
__device__ inline void load16_lds(const void* g, void* l) {
    __builtin_amdgcn_global_load_lds((const u32g*)g, (u32l*)l, 16, 0, 0);
}

// ================= weight transpose + bf16 convert: Wt[n][k] = bf16(W[k][n]) =================
__global__ __launch_bounds__(256) void wtrans(const float* __restrict__ W,
                                              unsigned short* __restrict__ Wt,
                                              int K, int N) {
    __shared__ unsigned short tile[64][72];
    int kb = blockIdx.y * 64, nb = blockIdx.x * 64;
    {
        int k = threadIdx.x >> 2;
        int n0 = (threadIdx.x & 3) * 16;
#pragma unroll
        for (int q = 0; q < 4; ++q) {
            float4 v = *(const float4*)(W + (size_t)(kb + k) * N + nb + n0 + q * 4);
            tile[k][n0 + q * 4 + 0] = f2bf(v.x);
            tile[k][n0 + q * 4 + 1] = f2bf(v.y);
            tile[k][n0 + q * 4 + 2] = f2bf(v.z);
            tile[k][n0 + q * 4 + 3] = f2bf(v.w);
        }
    }
    __syncthreads();
    {
        int n = threadIdx.x >> 2;
        int k0 = (threadIdx.x & 3) * 16;
#pragma unroll
        for (int q = 0; q < 4; ++q) {
            ushort4 u;
            u.x = tile[k0 + q * 4 + 0][n];
            u.y = tile[k0 + q * 4 + 1][n];
            u.z = tile[k0 + q * 4 + 2][n];
            u.w = tile[k0 + q * 4 + 3][n];
            *(ushort4*)(Wt + (size_t)(nb + n) * K + kb + k0 + q * 4) = u;
        }
    }
}

// ================= CSR build (by dst) =================
__global__ __launch_bounds__(256) void csr_count(const int* __restrict__ dst, int* __restrict__ cnt) {
    int e = blockIdx.x * 256 + threadIdx.x;
    if (e < NEDGES) atomicAdd(&cnt[dst[e]], 1);
}

__global__ __launch_bounds__(1024) void csr_scan(const int* __restrict__ cnt,
                                                 int* __restrict__ offs,
                                                 int* __restrict__ cursor,
                                                 float* __restrict__ dis) {
    __shared__ int part[1024];
    int t = threadIdx.x;
    int base = t * 32;
    int s = 0;
#pragma unroll
    for (int i = 0; i < 32; ++i) s += cnt[base + i];
    part[t] = s;
    __syncthreads();
    for (int off = 1; off < 1024; off <<= 1) {
        int v = (t >= off) ? part[t - off] : 0;
        __syncthreads();
        part[t] += v;
        __syncthreads();
    }
    int run = (t == 0) ? 0 : part[t - 1];
#pragma unroll
    for (int i = 0; i < 32; ++i) {
        int c = cnt[base + i];
        offs[base + i] = run;
        cursor[base + i] = run;
        dis[base + i] = rsqrtf((float)(c + 1));
        run += c;
    }
    if (t == 1023) offs[NNODES] = run;
}

__global__ __launch_bounds__(256) void csr_fill(const int* __restrict__ src,
                                                const int* __restrict__ dst,
                                                const float* __restrict__ dis,
                                                int* __restrict__ cursor,
                                                int* __restrict__ csr_src,
                                                float* __restrict__ csr_w) {
    int e = blockIdx.x * 256 + threadIdx.x;
    if (e >= NEDGES) return;
    int s = src[e], d = dst[e];
    int pos = atomicAdd(&cursor[d], 1);
    csr_src[pos] = s;
    csr_w[pos] = dis[s] * dis[d];
}

// ================= gather aggregation -> bf16 out =================
// BN=1: apply per-channel scale/shift + relu to every gathered row (fused BN+ReLU).
template<int F, int BFIN, int BN>
__global__ __launch_bounds__(256) void gcn_gather(const void* __restrict__ Xv,
                                                  const int* __restrict__ offs,
                                                  const int* __restrict__ csr_src,
                                                  const float* __restrict__ csr_w,
                                                  const float* __restrict__ dis,
                                                  const float* __restrict__ scale,
                                                  const float* __restrict__ shift,
                                                  unsigned short* __restrict__ out) {
    constexpr int CPL = F / 64;          // 2 (F=128) or 8 (F=512)
    int wave = threadIdx.x >> 6, lane = threadIdx.x & 63;
    int node = blockIdx.x * 4 + wave;
    int c0 = lane * CPL;
    float acc[CPL];
#pragma unroll
    for (int q = 0; q < CPL; ++q) acc[q] = 0.f;
    float sc[CPL], sh[CPL];
    if (BN) {
#pragma unroll
        for (int q = 0; q < CPL; ++q) { sc[q] = scale[c0 + q]; sh[q] = shift[c0 + q]; }
    }
    float sw = dis[node]; sw *= sw;

    int e0 = offs[node], e1 = offs[node + 1];
    // self term (e = -1) then edges
    for (int e = e0 - 1; e < e1; ++e) {
        int s; float w;
        if (e < e0) { s = node; w = sw; }
        else        { s = csr_src[e]; w = csr_w[e]; }
        if (BFIN) {
            const unsigned short* r = (const unsigned short*)Xv + (size_t)s * F + c0;
#pragma unroll
            for (int q = 0; q < (CPL + 3) / 4; ++q) {
                ushort4 u = *(const ushort4*)(r + q * 4);
                float v0 = bf2f(u.x), v1 = bf2f(u.y), v2 = bf2f(u.z), v3 = bf2f(u.w);
                if (BN) {
                    v0 = fmaxf(v0 * sc[q * 4 + 0] + sh[q * 4 + 0], 0.f);
                    v1 = fmaxf(v1 * sc[q * 4 + 1] + sh[q * 4 + 1], 0.f);
                    v2 = fmaxf(v2 * sc[q * 4 + 2] + sh[q * 4 + 2], 0.f);
                    v3 = fmaxf(v3 * sc[q * 4 + 3] + sh[q * 4 + 3], 0.f);
                }
                acc[q * 4 + 0] += w * v0; acc[q * 4 + 1] += w * v1;
                acc[q * 4 + 2] += w * v2; acc[q * 4 + 3] += w * v3;
            }
        } else if (CPL == 2) {
            float2 u = *(const float2*)((const float*)Xv + (size_t)s * F + c0);
            acc[0] += w * u.x; acc[1] += w * u.y;
        } else {
#pragma unroll
            for (int q = 0; q < (CPL + 3) / 4; ++q) {
                float4 u = *(const float4*)((const float*)Xv + (size_t)s * F + c0 + q * 4);
                acc[q * 4 + 0] += w * u.x; acc[q * 4 + 1] += w * u.y;
                acc[q * 4 + 2] += w * u.z; acc[q * 4 + 3] += w * u.w;
            }
        }
    }

    unsigned short* o = out + (size_t)node * F + c0;
    if (CPL == 2) {
        ushort2 u; u.x = f2bf(acc[0]); u.y = f2bf(acc[1]);
        *(ushort2*)o = u;
    } else {
#pragma unroll
        for (int q = 0; q < (CPL + 3) / 4; ++q) {
            ushort4 u;
            u.x = f2bf(acc[q * 4 + 0]); u.y = f2bf(acc[q * 4 + 1]);
            u.z = f2bf(acc[q * 4 + 2]); u.w = f2bf(acc[q * 4 + 3]);
            *(ushort4*)(o + q * 4) = u;
        }
    }
}

// ================= bf16 MFMA GEMM: C[M][N] = A[M][K] @ B (Bt[N][K]) =================
// 128x128 tile, BK=64, 4 waves. global_load_lds staging (no VGPR roundtrip, no spills).
// LDS XOR-swizzle via pre-swizzled global source (linear dest) + swizzled ds_read.
// CBF16=1: LDS-staged coalesced bf16 store. STATS=1: fused per-column sum/sumsq atomics.
template<int EPI, int CBF16, int STATS>
__global__ __launch_bounds__(256, 2) void gemm_mfma(const unsigned short* __restrict__ A,
                                                    const unsigned short* __restrict__ Bt,
                                                    const float* __restrict__ bias,
                                                    void* __restrict__ Cv,
                                                    float* __restrict__ gsum,
                                                    float* __restrict__ gsq,
                                                    int M, int N, int K) {
    constexpr int BM = 128, BN = 128, BK = 64;
    __shared__ unsigned short smem[128 * 136];   // K-loop: As[0..8191], Bs[8192..16383]; epilogue: C tile 128x136
    unsigned short* As = smem;
    unsigned short* Bs = smem + BM * BK;

    const int tid = threadIdx.x;
    const int lane = tid & 63;
    const int wave = tid >> 6;
    const int wr = wave >> 1, wc = wave & 1;

    // XCD-bijective swizzle (nwg % 8 == 0 for all our grids)
    const int nwg = gridDim.x * gridDim.y;
    const int wg = blockIdx.y * gridDim.x + blockIdx.x;
    const int cpx = nwg >> 3;
    const int swz = (wg & 7) * cpx + (wg >> 3);
    const int m0 = (swz / gridDim.x) * BM, n0 = (swz % gridDim.x) * BN;

    // staging source map: linear LDS byte Ld = i*4096 + tid*16 -> row r = i*32 + (tid>>3),
    // row-byte subL = (tid&7)*16; content there must be global byte subL ^ ((r&7)<<4).
    const int sub = ((tid & 7) * 16) ^ (((tid >> 3) & 7) << 4);
    const int rbase = tid >> 3;
    const char* Ab = (const char*)A + sub;
    const char* Bb = (const char*)Bt + sub;

    f32x4 acc[4][4] = {};

    for (int k0 = 0; k0 < K; k0 += BK) {
        __syncthreads();   // previous iteration's LDS reads complete before overwrite
#pragma unroll
        for (int i = 0; i < 4; ++i) {
            int r = i * 32 + rbase;
            load16_lds(Ab + ((size_t)(m0 + r) * K + k0) * 2, (char*)As + i * 4096 + tid * 16);
            load16_lds(Bb + ((size_t)(n0 + r) * K + k0) * 2, (char*)Bs + i * 4096 + tid * 16);
        }
        __syncthreads();   // compiler drains vmcnt before barrier -> LDS tile ready
#pragma unroll
        for (int ks = 0; ks < 2; ++ks) {
            bf16x8 af[4], bfr[4];
#pragma unroll
            for (int m = 0; m < 4; ++m) {
                int row = wr * 64 + m * 16 + (lane & 15);
                int s = (ks * 64 + ((lane >> 4) * 16)) ^ ((row & 7) << 4);
                af[m] = *(const bf16x8*)((const char*)As + row * 128 + s);
            }
#pragma unroll
            for (int n = 0; n < 4; ++n) {
                int row = wc * 64 + n * 16 + (lane & 15);
                int s = (ks * 64 + ((lane >> 4) * 16)) ^ ((row & 7) << 4);
                bfr[n] = *(const bf16x8*)((const char*)Bs + row * 128 + s);
            }
#pragma unroll
            for (int m = 0; m < 4; ++m)
#pragma unroll
                for (int n = 0; n < 4; ++n)
                    acc[m][n] = __builtin_amdgcn_mfma_f32_16x16x32_bf16(af[m], bfr[n], acc[m][n], 0, 0, 0);
        }
    }

    // ---- epilogue ----
    if (CBF16) {
        __syncthreads();                         // MFMA LDS reads done; reuse smem for C tile
        float cs[4], cq[4];
#pragma unroll
        for (int n = 0; n < 4; ++n) { cs[n] = 0.f; cq[n] = 0.f; }
#pragma unroll
        for (int n = 0; n < 4; ++n) {
            int col = wc * 64 + n * 16 + (lane & 15);
            float bsv = bias[n0 + col];
#pragma unroll
            for (int m = 0; m < 4; ++m) {
                int rbase2 = wr * 64 + m * 16 + ((lane >> 4) << 2);
#pragma unroll
                for (int j = 0; j < 4; ++j) {
                    float v = acc[m][n][j] + bsv;
                    if (STATS) { cs[n] += v; cq[n] += v * v; }
                    if (EPI == 1) v = fmaxf(v, 0.f);
                    smem[(rbase2 + j) * 136 + col] = f2bf(v);
                }
            }
        }
        if (STATS) {
#pragma unroll
            for (int n = 0; n < 4; ++n) {
                cs[n] += __shfl_xor(cs[n], 16); cs[n] += __shfl_xor(cs[n], 32);
                cq[n] += __shfl_xor(cq[n], 16); cq[n] += __shfl_xor(cq[n], 32);
            }
            if (lane < 16) {
#pragma unroll
                for (int n = 0; n < 4; ++n) {
                    int col = n0 + wc * 64 + n * 16 + lane;
                    atomicAdd(&gsum[col], cs[n]);
                    atomicAdd(&gsq[col],  cq[n]);
                }
            }
        }
        __syncthreads();
#pragma unroll
        for (int it = 0; it < 8; ++it) {
            int r = it * 16 + (tid >> 4);
            int ch = tid & 15;
            int4 v = *(const int4*)&smem[r * 136 + ch * 8];
            *(int4*)((unsigned short*)Cv + (size_t)(m0 + r) * N + n0 + ch * 8) = v;
        }
    } else {
#pragma unroll
        for (int m = 0; m < 4; ++m) {
            int row = m0 + wr * 64 + m * 16 + ((lane >> 4) << 2);
#pragma unroll
            for (int n = 0; n < 4; ++n) {
                int col = n0 + wc * 64 + n * 16 + (lane & 15);
                float bsv = bias[col];
#pragma unroll
                for (int j = 0; j < 4; ++j) {
                    float v = acc[m][n][j] + bsv;
                    if (EPI == 1) v = fmaxf(v, 0.f);
                    ((float*)Cv)[(size_t)(row + j) * N + col] = v;
                }
            }
        }
    }
}

__global__ void bn_finalize(const float* __restrict__ sum, const float* __restrict__ sq,
                            const float* __restrict__ w, const float* __restrict__ b,
                            float* __restrict__ scale, float* __restrict__ shift,
                            int cols, float invN) {
    int c = blockIdx.x * blockDim.x + threadIdx.x;
    if (c >= cols) return;
    float mu = sum[c] * invN;
    float var = sq[c] * invN - mu * mu;
    float sc = rsqrtf(var + 1e-5f) * w[c];
    scale[c] = sc;
    shift[c] = b[c] - mu * sc;
}

// ---------------- fused: LN1 stats + per-graph per-channel max/min of relu(bn(h2)) ----------------
// one block per graph (32 rows); thread owns 4 fixed channels -> scale/shift in regs, coalesced rows.
__global__ __launch_bounds__(256) void bn_stats_pool(const unsigned short* __restrict__ H,
                                                     const float* __restrict__ scale,
                                                     const float* __restrict__ shift,
                                                     float* __restrict__ gmax,
                                                     float* __restrict__ gmin,
                                                     double* __restrict__ lnacc) {
    int g = blockIdx.x;
    int c0 = threadIdx.x * 4;
    float4 sc = *(const float4*)(scale + c0);
    float4 sh = *(const float4*)(shift + c0);
    float4 mx = make_float4(-1e30f, -1e30f, -1e30f, -1e30f);
    float4 mn = make_float4(1e30f, 1e30f, 1e30f, 1e30f);
    float lsum = 0.f, lsq = 0.f;
    const unsigned short* row = H + (size_t)g * 32 * HID2 + c0;
#pragma unroll 4
    for (int n = 0; n < 32; ++n, row += HID2) {
        ushort4 u = *(const ushort4*)row;
        float a = fmaxf(bf2f(u.x) * sc.x + sh.x, 0.f);
        float b = fmaxf(bf2f(u.y) * sc.y + sh.y, 0.f);
        float c = fmaxf(bf2f(u.z) * sc.z + sh.z, 0.f);
        float d = fmaxf(bf2f(u.w) * sc.w + sh.w, 0.f);
        mx.x = fmaxf(mx.x, a); mx.y = fmaxf(mx.y, b); mx.z = fmaxf(mx.z, c); mx.w = fmaxf(mx.w, d);
        mn.x = fminf(mn.x, a); mn.y = fminf(mn.y, b); mn.z = fminf(mn.z, c); mn.w = fminf(mn.w, d);
        lsum += a + b + c + d;
        lsq  += a * a + b * b + c * c + d * d;
    }
    *(float4*)(gmax + (size_t)g * HID2 + c0) = mx;
    *(float4*)(gmin + (size_t)g * HID2 + c0) = mn;
    for (int o = 32; o > 0; o >>= 1) {
        lsum += __shfl_down(lsum, o);
        lsq  += __shfl_down(lsq, o);
    }
    __shared__ float w1[4], w2[4];
    int wid = threadIdx.x >> 6, lane = threadIdx.x & 63;
    if (lane == 0) { w1[wid] = lsum; w2[wid] = lsq; }
    __syncthreads();
    if (threadIdx.x == 0) {
        atomicAdd(lnacc,     (double)(w1[0] + w1[1] + w1[2] + w1[3]));
        atomicAdd(lnacc + 1, (double)(w2[0] + w2[1] + w2[2] + w2[3]));
    }
}

// ---------------- pool finalize: pooled = a>=0 ? a*max+c : a*min+c  (LN affine is monotone per sign) ----------------
__global__ __launch_bounds__(256) void pool_fin(const float* __restrict__ gmax,
                                                const float* __restrict__ gmin,
                                                const float* __restrict__ a,
                                                const float* __restrict__ c,
                                                unsigned short* __restrict__ P) {
    int i = blockIdx.x * 256 + threadIdx.x;            // over NGRAPH*HID2/4
    int c0 = (i * 4) & (HID2 - 1);
    float4 av = *(const float4*)(a + c0);
    float4 cv = *(const float4*)(c + c0);
    float4 mx = ((const float4*)gmax)[i];
    float4 mn = ((const float4*)gmin)[i];
    float4 r;
    r.x = (av.x >= 0.f ? av.x * mx.x : av.x * mn.x) + cv.x;
    r.y = (av.y >= 0.f ? av.y * mx.y : av.y * mn.y) + cv.y;
    r.z = (av.z >= 0.f ? av.z * mx.z : av.z * mn.z) + cv.z;
    r.w = (av.w >= 0.f ? av.w * mx.w : av.w * mn.w) + cv.w;
    ushort4 o;
    o.x = f2bf(r.x); o.y = f2bf(r.y); o.z = f2bf(r.z); o.w = f2bf(r.w);
    ((ushort4*)P)[i] = o;
}

// ---------------- global stats (LN2 over z, fp32) ----------------
__global__ __launch_bounds__(256) void global_stats(const float* __restrict__ X, int total4, double* acc) {
    float s = 0.f, ss = 0.f;
    for (int t = blockIdx.x * 256 + threadIdx.x; t < total4; t += gridDim.x * 256) {
        float4 v = ((const float4*)X)[t];
        s  += v.x + v.y + v.z + v.w;
        ss += v.x * v.x + v.y * v.y + v.z * v.z + v.w * v.w;
    }
    for (int o = 32; o > 0; o >>= 1) {
        s += __shfl_down(s, o);
        ss += __shfl_down(ss, o);
    }
    __shared__ float w1[4], w2[4];
    int wid = threadIdx.x >> 6, lane = threadIdx.x & 63;
    if (lane == 0) { w1[wid] = s; w2[wid] = ss; }
    __syncthreads();
    if (threadIdx.x == 0) {
        atomicAdd(acc,     (double)(w1[0] + w1[1] + w1[2] + w1[3]));
        atomicAdd(acc + 1, (double)(w2[0] + w2[1] + w2[2] + w2[3]));
    }
}

// ---------------- LN finalize: per-channel affine a[c], c[c] ----------------
__global__ void ln_finalize(const double* __restrict__ acc, const float* __restrict__ w,
                            const float* __restrict__ b, float* __restrict__ a,
                            float* __restrict__ c, int cols, double invCount) {
    __shared__ float smu, sinv;
    if (threadIdx.x == 0) {
        double mu  = acc[0] * invCount;
        double var = acc[1] * invCount - mu * mu;
        if (var < 0.0) var = 0.0;
        float stdv = sqrtf((float)var);
        smu = (float)mu;
        sinv = 1.0f / (stdv + 1e-5f);
    }
    __syncthreads();
    int ci = threadIdx.x;
    if (ci < cols) {
        float A = sinv * w[ci];
        a[ci] = A;
        c[ci] = b[ci] - smu * A;
    }
}

// ---------------- fused LN2 + final GEMM [1024,512]@[512,20] + log_softmax ----------------
__global__ __launch_bounds__(64) void gemm4_lsm(const float* __restrict__ Z,
                                                const float* __restrict__ a,
                                                const float* __restrict__ c,
                                                const float* __restrict__ W,
                                                const float* __restrict__ bias,
                                                float* __restrict__ out) {
    __shared__ float zs[HID1];
    __shared__ float logits[NCLS];
    __shared__ float smax, slse;
    int m = blockIdx.x;
    for (int k = threadIdx.x; k < HID1; k += 64)
        zs[k] = Z[(size_t)m * HID1 + k] * a[k] + c[k];
    __syncthreads();
    if (threadIdx.x < NCLS) {
        float acc = bias[threadIdx.x];
        for (int k = 0; k < HID1; ++k)
            acc += zs[k] * W[k * NCLS + threadIdx.x];
        logits[threadIdx.x] = acc;
    }
    __syncthreads();
    if (threadIdx.x == 0) {
        float mx = -1e30f;
        for (int j = 0; j < NCLS; ++j) mx = fmaxf(mx, logits[j]);
        float s = 0.f;
        for (int j = 0; j < NCLS; ++j) s += expf(logits[j] - mx);
        smax = mx; slse = logf(s);
    }
    __syncthreads();
    if (threadIdx.x < NCLS)
        out[(size_t)m * NCLS + threadIdx.x] = logits[threadIdx.x] - smax - slse;
}

// ======================== launch ========================
extern "C" void kernel_launch(void* const* d_in, const int* in_sizes, int n_in,
                              void* d_out, int out_size, void* d_ws, size_t ws_size,
                              hipStream_t stream) {
    const float* x       = (const float*)d_in[0];
    const int*   ei      = (const int*)d_in[1];
    const int*   src     = ei;
    const int*   dst     = ei + NEDGES;
    const float* conv1_w = (const float*)d_in[3];
    const float* conv1_b = (const float*)d_in[4];
    const float* bn1_w   = (const float*)d_in[5];
    const float* bn1_b   = (const float*)d_in[6];
    const float* conv2_w = (const float*)d_in[7];
    const float* conv2_b = (const float*)d_in[8];
    const float* bn2_w   = (const float*)d_in[9];
    const float* bn2_b   = (const float*)d_in[10];
    const float* ln1_w   = (const float*)d_in[11];
    const float* ln1_b   = (const float*)d_in[12];
    const float* lin1_w  = (const float*)d_in[13];
    const float* lin1_b  = (const float*)d_in[14];
    const float* ln2_w   = (const float*)d_in[15];
    const float* ln2_b   = (const float*)d_in[16];
    const float* lin2_w  = (const float*)d_in[17];
    const float* lin2_b  = (const float*)d_in[18];
    float* out = (float*)d_out;

    // ---- workspace layout (peak 120 MB) ----
    char* ws = (char*)d_ws;
    const size_t KB = 1024, MB = 1048576;
    float*          dis     = (float*)(ws + 0);            // 128K
    float*          sF      = (float*)(ws + 128 * KB);     // 64K stats
    unsigned short* w1t     = (unsigned short*)(ws + 256 * KB);   // [512][128]  128K
    unsigned short* w2t     = (unsigned short*)(ws + 512 * KB);   // [1024][512] 1M
    unsigned short* w3t     = (unsigned short*)(ws + 1536 * KB);  // [512][1024] 1M
    int*            cnt     = (int*)(ws + 2560 * KB);      // 128K
    int*            offs    = (int*)(ws + 2688 * KB);      // 128K+4 (192K reserved)
    int*            cursor  = (int*)(ws + 2880 * KB);      // 128K
    int*            csr_src = (int*)(ws + 3 * MB);         // 1M
    float*          csr_w   = (float*)(ws + 4 * MB);       // 1M
    unsigned short* pool    = (unsigned short*)(ws + 5 * MB);   // [1024][1024] bf16 2M
    float*          z       = (float*)(ws + 7 * MB);       // [1024][512] f32 2M
    unsigned short* agg1    = (unsigned short*)(ws + 16 * MB);  // [N,128] bf16 8M   (16-24)
    unsigned short* h1      = (unsigned short*)(ws + 24 * MB);  // [N,512] bf16 32M  (24-56)
    unsigned short* h2      = (unsigned short*)(ws + 16 * MB);  // [N,1024] bf16 64M (16-80, overlays dead agg1+h1)
    float*          gmax    = (float*)(ws + 80 * MB);      // [G,1024] f32 4M (80-84)
    float*          gmin    = (float*)(ws + 84 * MB);      // [G,1024] f32 4M (84-88)
    unsigned short* agg2    = (unsigned short*)(ws + 88 * MB);  // [N,512] bf16 32M  (88-120)

    float* bn1_sum = sF + 0,      *bn1_sq    = sF + 512;
    float* bn1_scale = sF + 1024, *bn1_shift = sF + 1536;
    float* bn2_sum = sF + 2048,   *bn2_sq    = sF + 3072;
    float* bn2_scale = sF + 4096, *bn2_shift = sF + 5120;
    float* ln1_a = sF + 6144, *ln1_c = sF + 7168;
    float* ln2_a = sF + 8192, *ln2_c = sF + 8704;
    double* lnacc = (double*)(sF + 9216);   // [0,1]=ln1  [2,3]=ln2

    hipMemsetAsync(sF, 0, 40960, stream);
    hipMemsetAsync(cnt, 0, NNODES * 4, stream);

    // ---- weight transposes (bf16) ----
    wtrans<<<dim3(HID1 / 64, FIN / 64),  256, 0, stream>>>(conv1_w, w1t, FIN, HID1);
    wtrans<<<dim3(HID2 / 64, HID1 / 64), 256, 0, stream>>>(conv2_w, w2t, HID1, HID2);
    wtrans<<<dim3(HID1 / 64, HID2 / 64), 256, 0, stream>>>(lin1_w,  w3t, HID2, HID1);

    // ---- CSR build (by dst) + dis ----
    csr_count<<<(NEDGES + 255) / 256, 256, 0, stream>>>(dst, cnt);
    csr_scan<<<1, 1024, 0, stream>>>(cnt, offs, cursor, dis);
    csr_fill<<<(NEDGES + 255) / 256, 256, 0, stream>>>(src, dst, dis, cursor, csr_src, csr_w);

    // ---- conv1: agg1 = A @ x ; h1 = agg1 @ W1 + b1 (+ fused bn1 col stats; h1 stays RAW) ----
    gcn_gather<FIN, 0, 0><<<NNODES / 4, 256, 0, stream>>>(x, offs, csr_src, csr_w, dis, nullptr, nullptr, agg1);
    gemm_mfma<0, 1, 1><<<dim3(HID1 / 128, NNODES / 128), 256, 0, stream>>>(agg1, w1t, conv1_b, h1, bn1_sum, bn1_sq, NNODES, HID1, FIN);

    // ---- bn1 coeffs; conv2 gather applies BN1+ReLU on the fly ----
    bn_finalize<<<(HID1 + 255) / 256, 256, 0, stream>>>(bn1_sum, bn1_sq, bn1_w, bn1_b, bn1_scale, bn1_shift, HID1, 1.0f / NNODES);
    gcn_gather<HID1, 1, 1><<<NNODES / 4, 256, 0, stream>>>(h1, offs, csr_src, csr_w, dis, bn1_scale, bn1_shift, agg2);
    gemm_mfma<0, 1, 1><<<dim3(HID2 / 128, NNODES / 128), 256, 0, stream>>>(agg2, w2t, conv2_b, h2, bn2_sum, bn2_sq, NNODES, HID2, HID1);

    // ---- bn2 coeffs; single pass: LN1 stats + per-graph max/min of relu(bn(h2)) ----
    bn_finalize<<<(HID2 + 255) / 256, 256, 0, stream>>>(bn2_sum, bn2_sq, bn2_w, bn2_b, bn2_scale, bn2_shift, HID2, 1.0f / NNODES);
    bn_stats_pool<<<NGRAPH, 256, 0, stream>>>(h2, bn2_scale, bn2_shift, gmax, gmin, lnacc);

    // ---- LN1 affine + pool finalize (monotone-affine max) ----
    ln_finalize<<<1, HID2, 0, stream>>>(lnacc, ln1_w, ln1_b, ln1_a, ln1_c, HID2, 1.0 / ((double)NNODES * HID2));
    pool_fin<<<NGRAPH * HID2 / 4 / 256, 256, 0, stream>>>(gmax, gmin, ln1_a, ln1_c, pool);

    // ---- lin1 + relu (MFMA, f32 out) ----
    gemm_mfma<1, 0, 0><<<dim3(HID1 / 128, NGRAPH / 128), 256, 0, stream>>>(pool, w3t, lin1_b, z, nullptr, nullptr, NGRAPH, HID1, HID2);

    // ---- LN2 + lin2 + log_softmax ----
    global_stats<<<512, 256, 0, stream>>>(z, NGRAPH * HID1 / 4, lnacc + 2);
    ln_finalize<<<1, HID1, 0, stream>>>(lnacc + 2, ln2_w, ln2_b, ln2_a, ln2_c, HID1, 1.0 / ((double)NGRAPH * HID1));
    gemm4_lsm<<<NGRAPH, 64, 0, stream>>>(z, ln2_a, ln2_c, lin2_w, lin2_b, out);
}